// Round 5
// baseline (413.778 us; speedup 1.0000x reference)
//
#include <hip/hip_runtime.h>
#include <math.h>

typedef unsigned short u16;
typedef __attribute__((ext_vector_type(8))) short v8bf;
typedef __attribute__((ext_vector_type(4))) float f32x4;

#define N_TOK 4096
#define DMODEL 512
#define NHEAD 8
#define HDIM 64
#define CANDN 64
#define ATT_SCALE 0.125f
#define MAX_NORM_F 0.99999f
#define WL_CAP 8192

__device__ __forceinline__ float bf2f(u16 u) {
  union { unsigned int i; float f; } v; v.i = ((unsigned int)u) << 16; return v.f;
}
__device__ __forceinline__ u16 f2bf(float f) {
  union { float f; unsigned int i; } v; v.f = f;
  unsigned int x = v.i;
  return (u16)((x + 0x7fffu + ((x >> 16) & 1u)) >> 16);
}
__device__ __forceinline__ uint4 load_pack8(const float* __restrict__ p) {
  const float4 x0 = *(const float4*)p;
  const float4 x1 = *(const float4*)(p + 4);
  union { u16 h[8]; uint4 u; } r;
  r.h[0] = f2bf(x0.x); r.h[1] = f2bf(x0.y); r.h[2] = f2bf(x0.z); r.h[3] = f2bf(x0.w);
  r.h[4] = f2bf(x1.x); r.h[5] = f2bf(x1.y); r.h[6] = f2bf(x1.z); r.h[7] = f2bf(x1.w);
  return r.u;
}

// ---------------------------------------------------------------------------
// GEMM 128x128 tile, BK=32, 4 waves x (4x4) 16x16x32 bf16 MFMAs (unchanged).
// ---------------------------------------------------------------------------
__global__ __launch_bounds__(256) void gemm_qkv_kernel(
    const float* __restrict__ query, const float* __restrict__ key_, const float* __restrict__ value,
    const float* __restrict__ Wq, const float* __restrict__ bq,
    const float* __restrict__ Wk, const float* __restrict__ bk,
    const float* __restrict__ Wv, const float* __restrict__ bv,
    float* __restrict__ Qp, float* __restrict__ Kp, u16* __restrict__ Vb)
{
  const int z = blockIdx.z;
  const float* A    = (z == 0) ? query : (z == 1) ? key_ : value;
  const float* W    = (z == 0) ? Wq    : (z == 1) ? Wk   : Wv;
  const float* bias = (z == 0) ? bq    : (z == 1) ? bk   : bv;

  __shared__ u16 As[128 * 40];
  __shared__ u16 Ws[128 * 40];

  const int tid  = threadIdx.x;
  const int lane = tid & 63;
  const int wave = tid >> 6;
  const int row4 = tid >> 2;
  const int seg  = tid & 3;

  const int bm = blockIdx.x * 128;
  const int bn = blockIdx.y * 128;
  const int wm = (wave & 1) * 64;
  const int wn = (wave >> 1) * 64;
  const int l15 = lane & 15;
  const int quad = lane >> 4;

  f32x4 acc[4][4] = {};

  for (int kt = 0; kt < DMODEL; kt += 32) {
    uint4 a0 = load_pack8(A + (bm + row4) * DMODEL + kt + seg * 8);
    uint4 a1 = load_pack8(A + (bm + row4 + 64) * DMODEL + kt + seg * 8);
    uint4 w0 = load_pack8(W + (bn + row4) * DMODEL + kt + seg * 8);
    uint4 w1 = load_pack8(W + (bn + row4 + 64) * DMODEL + kt + seg * 8);
    __syncthreads();
    *(uint4*)&As[row4 * 40 + seg * 8] = a0;
    *(uint4*)&As[(row4 + 64) * 40 + seg * 8] = a1;
    *(uint4*)&Ws[row4 * 40 + seg * 8] = w0;
    *(uint4*)&Ws[(row4 + 64) * 40 + seg * 8] = w1;
    __syncthreads();
    v8bf af[4], bfr[4];
#pragma unroll
    for (int i = 0; i < 4; ++i)
      af[i] = *(const v8bf*)&As[(wm + i * 16 + l15) * 40 + quad * 8];
#pragma unroll
    for (int j = 0; j < 4; ++j)
      bfr[j] = *(const v8bf*)&Ws[(wn + j * 16 + l15) * 40 + quad * 8];
#pragma unroll
    for (int i = 0; i < 4; ++i)
#pragma unroll
      for (int j = 0; j < 4; ++j)
        acc[i][j] = __builtin_amdgcn_mfma_f32_16x16x32_bf16(af[i], bfr[j], acc[i][j], 0, 0, 0);
  }

#pragma unroll
  for (int j = 0; j < 4; ++j) {
    const int cg = bn + wn + j * 16 + l15;
    const float bval = bias[cg];
    const int h = cg >> 6, hd = cg & 63;
#pragma unroll
    for (int i = 0; i < 4; ++i) {
      const int rbase = bm + wm + i * 16 + quad * 4;
#pragma unroll
      for (int r = 0; r < 4; ++r) {
        const int idx = (((h << 12) + rbase + r) << 6) + hd;
        const float val = acc[i][j][r] + bval;
        if (z == 2)      Vb[idx] = f2bf(val);
        else if (z == 1) Kp[idx] = val;
        else             Qp[idx] = val;
      }
    }
  }
}

__global__ __launch_bounds__(256) void gemm_out_kernel(
    const u16* __restrict__ A, const float* __restrict__ W,
    const float* __restrict__ bias, float* __restrict__ O)
{
  __shared__ u16 As[128 * 40];
  __shared__ u16 Ws[128 * 40];

  const int tid  = threadIdx.x;
  const int lane = tid & 63;
  const int wave = tid >> 6;
  const int row4 = tid >> 2;
  const int seg  = tid & 3;

  const int bm = blockIdx.x * 128;
  const int bn = blockIdx.y * 128;
  const int wm = (wave & 1) * 64;
  const int wn = (wave >> 1) * 64;
  const int l15 = lane & 15;
  const int quad = lane >> 4;

  f32x4 acc[4][4] = {};

  for (int kt = 0; kt < DMODEL; kt += 32) {
    uint4 a0 = *(const uint4*)(A + (bm + row4) * DMODEL + kt + seg * 8);
    uint4 a1 = *(const uint4*)(A + (bm + row4 + 64) * DMODEL + kt + seg * 8);
    uint4 w0 = load_pack8(W + (bn + row4) * DMODEL + kt + seg * 8);
    uint4 w1 = load_pack8(W + (bn + row4 + 64) * DMODEL + kt + seg * 8);
    __syncthreads();
    *(uint4*)&As[row4 * 40 + seg * 8] = a0;
    *(uint4*)&As[(row4 + 64) * 40 + seg * 8] = a1;
    *(uint4*)&Ws[row4 * 40 + seg * 8] = w0;
    *(uint4*)&Ws[(row4 + 64) * 40 + seg * 8] = w1;
    __syncthreads();
    v8bf af[4], bfr[4];
#pragma unroll
    for (int i = 0; i < 4; ++i)
      af[i] = *(const v8bf*)&As[(wm + i * 16 + l15) * 40 + quad * 8];
#pragma unroll
    for (int j = 0; j < 4; ++j)
      bfr[j] = *(const v8bf*)&Ws[(wn + j * 16 + l15) * 40 + quad * 8];
#pragma unroll
    for (int i = 0; i < 4; ++i)
#pragma unroll
      for (int j = 0; j < 4; ++j)
        acc[i][j] = __builtin_amdgcn_mfma_f32_16x16x32_bf16(af[i], bfr[j], acc[i][j], 0, 0, 0);
  }

#pragma unroll
  for (int j = 0; j < 4; ++j) {
    const int cg = bn + wn + j * 16 + l15;
    const float bval = bias[cg];
#pragma unroll
    for (int i = 0; i < 4; ++i) {
      const int rbase = bm + wm + i * 16 + quad * 4;
#pragma unroll
      for (int r = 0; r < 4; ++r)
        O[(rbase + r) * DMODEL + cg] = acc[i][j][r] + bval;
    }
  }
}

// ---------------------------------------------------------------------------
// Bins. Theory (R4 post-mortem): the np reference computes the whole pipeline
// in float32; its bins carry ~10-ulp GEMM noise, so ~1-3 elements straddle a
// floor() boundary vs exact math. Pass 1 computes f64 bins and FLAGS elements
// whose t is within an adaptive margin of an integer. Pass 2 re-derives only
// the flagged (~100) elements with bit-mimicry of np-f32:
//   - sequential f32 FMA dots k=0..511 (OpenBLAS microkernel order; if this
//     fails next lever is a kc=384 panel split: chain(0..383)+chain(384..511))
//   - numpy scalar pairwise-8-accumulator sum for the squared norm
//   - f32 projection multiply, f32 div/add/mul/floor
//   - glibc/musl fdlibm atan2f port, guarded by correctly-rounded f64 atan2
// ---------------------------------------------------------------------------

__global__ void wl_init_kernel(int* __restrict__ wl_count) { *wl_count = 0; }

__global__ __launch_bounds__(256) void bins_pass1_kernel(
    const float* __restrict__ query, const float* __restrict__ key_,
    const float* __restrict__ Wq, const float* __restrict__ Wk,
    int* __restrict__ qb, int* __restrict__ kb,
    int* __restrict__ wl_count, int* __restrict__ wl)
{
  const int tid = blockIdx.x * 256 + threadIdx.x;  // 0..65535
  const int n   = tid & 4095;
  const int h   = (tid >> 12) & 7;
  const int isk = tid >> 15;
  const float* X = isk ? key_ : query;
  const float* W = isk ? Wk : Wq;
  const float* xr = X + n * DMODEL;
  const float* w0 = W + (h * 64 + 0) * DMODEL;
  const float* w1 = W + (h * 64 + 1) * DMODEL;
  double a0 = 0.0, a1 = 0.0;  // biases are zero
  for (int c = 0; c < DMODEL; c += 4) {
    const float4 x = *(const float4*)(xr + c);
    const float4 u = *(const float4*)(w0 + c);
    const float4 v = *(const float4*)(w1 + c);
    a0 += (double)x.x * u.x; a1 += (double)x.x * v.x;
    a0 += (double)x.y * u.y; a1 += (double)x.y * v.y;
    a0 += (double)x.z * u.z; a1 += (double)x.z * v.z;
    a0 += (double)x.w * u.w; a1 += (double)x.w * v.w;
  }
  double ang = atan2(a1, a0);
  double t = (ang / 6.283185307179586 + 0.5) * 512.0;
  int b = (int)floor(t);
  b = b < 0 ? 0 : (b > 511 ? 511 : b);
  (isk ? kb : qb)[(h << 12) + n] = b;

  // flag boundary-risk elements for f32-mimic refinement
  const double r = sqrt(a0 * a0 + a1 * a1);
  const double dist = fabs(t - nearbyint(t));
  const double margin = fmin(0.45, 3.3e-4 / fmax(r, 1e-30) + 5e-5);
  if (dist < margin) {
    int idx = atomicAdd(wl_count, 1);
    if (idx < WL_CAP) wl[idx] = (isk << 15) | (h << 12) | n;
  }
}

// fdlibm (musl/glibc flt-32) atanf/atan2f port. Plain ops are IEEE-RN; the
// pragma blocks FMA contraction so op-for-op rounding matches libm.
__device__ float fdlibm_atanf(float x) {
#pragma clang fp contract(off)
  const float atanhi[4] = {4.6364760399e-01f, 7.8539812565e-01f,
                           9.8279368877e-01f, 1.5707962513e+00f};
  const float atanlo[4] = {5.0121582440e-09f, 3.7748947079e-08f,
                           3.4473217170e-08f, 7.5497894159e-08f};
  const float aT[5] = {3.3333328366e-01f, -1.9999158382e-01f, 1.4253635705e-01f,
                       -1.0648017377e-01f, 6.1687607318e-02f};
  unsigned ix = __float_as_uint(x);
  const unsigned sign = ix >> 31;
  ix &= 0x7fffffffu;
  int id;
  float z, w, s1, s2;
  if (ix >= 0x4c800000u) {  // |x| >= 2^26
    z = atanhi[3] + 0x1p-120f;
    return sign ? -z : z;
  }
  if (ix < 0x3ee00000u) {  // |x| < 0.4375
    if (ix < 0x39800000u) return x;  // |x| < 2^-12
    id = -1;
  } else {
    x = fabsf(x);
    if (ix < 0x3f980000u) {
      if (ix < 0x3f300000u) { id = 0; x = (2.0f * x - 1.0f) / (2.0f + x); }
      else                  { id = 1; x = (x - 1.0f) / (x + 1.0f); }
    } else {
      if (ix < 0x401c0000u) { id = 2; x = (x - 1.5f) / (1.0f + 1.5f * x); }
      else                  { id = 3; x = -1.0f / x; }
    }
  }
  z = x * x;
  w = z * z;
  s1 = z * (aT[0] + w * (aT[2] + w * aT[4]));
  s2 = w * (aT[1] + w * aT[3]);
  if (id < 0) return x - x * (s1 + s2);
  z = atanhi[id] - ((x * (s1 + s2) - atanlo[id]) - x);
  return sign ? -z : z;
}

__device__ float fdlibm_atan2f(float y, float x) {
#pragma clang fp contract(off)
  const float pi = 3.1415927410e+00f, pi_lo = -8.7422776573e-08f;
  const unsigned hx = __float_as_uint(x), hy = __float_as_uint(y);
  if (hx == 0x3f800000u) return fdlibm_atanf(y);
  const unsigned m = ((hy >> 31) & 1u) | ((hx >> 30) & 2u);
  const unsigned ix = hx & 0x7fffffffu, iy = hy & 0x7fffffffu;
  if (iy == 0u) {
    switch (m) { case 0: case 1: return y; case 2: return pi; default: return -pi; }
  }
  if (ix == 0u) return (m & 1u) ? -1.57079637050628662f : 1.57079637050628662f;
  float z;
  if (ix + (26u << 23) < iy) {
    z = 1.57079637050628662f;
    return (m & 1u) ? -z : z;
  }
  if ((m & 2u) && iy + (26u << 23) < ix) z = 0.0f;
  else z = fdlibm_atanf(fabsf(y / x));
  switch (m) {
    case 0: return z;
    case 1: return -z;
    case 2: return pi - (z - pi_lo);
    default: return (z - pi_lo) - pi;
  }
}

__global__ __launch_bounds__(64) void bins_pass2_kernel(
    const float* __restrict__ query, const float* __restrict__ key_,
    const float* __restrict__ Wq, const float* __restrict__ Wk,
    int* __restrict__ qb, int* __restrict__ kb,
    const int* __restrict__ wl_count, const int* __restrict__ wl)
{
  __shared__ float qv[64];
  __shared__ float qs[64];
  int cnt = *wl_count;
  if (cnt > WL_CAP) cnt = WL_CAP;
  const int d = threadIdx.x;
  for (int e = blockIdx.x; e < cnt; e += gridDim.x) {
    const int code = wl[e];
    const int n = code & 4095;
    const int h = (code >> 12) & 7;
    const int isk = (code >> 15) & 1;
    const float* xr = (isk ? key_ : query) + n * DMODEL;
    const float* wr = (isk ? Wk : Wq) + (h * 64 + d) * DMODEL;
    // sequential f32 FMA chain, k ascending (BLAS microkernel order)
    float acc = 0.0f;
    for (int k = 0; k < DMODEL; ++k) acc = __fmaf_rn(xr[k], wr[k], acc);
    {
#pragma clang fp contract(off)
      qv[d] = acc;
      qs[d] = acc * acc;  // np squares the f32 values elementwise
    }
    __syncthreads();
    if (d == 0) {
#pragma clang fp contract(off)
      // numpy pairwise_sum, n=64 scalar path: 8 accumulators, stride-8, tree
      float r0 = qs[0], r1 = qs[1], r2 = qs[2], r3 = qs[3];
      float r4 = qs[4], r5 = qs[5], r6 = qs[6], r7 = qs[7];
      for (int i = 8; i < 64; i += 8) {
        r0 += qs[i + 0]; r1 += qs[i + 1]; r2 += qs[i + 2]; r3 += qs[i + 3];
        r4 += qs[i + 4]; r5 += qs[i + 5]; r6 += qs[i + 6]; r7 += qs[i + 7];
      }
      const float ss = ((r0 + r1) + (r2 + r3)) + ((r4 + r5) + (r6 + r7));
      const float nrm = __fsqrt_rn(ss);
      const float s = fminf(1.0f, 0.99999f / fmaxf(nrm, 1e-12f));
      const float c0 = qv[0] * s;
      const float c1 = qv[1] * s;
      const float cr = (float)atan2((double)c1, (double)c0);  // CR fallback
      const float fd = fdlibm_atan2f(c1, c0);
      const float tol = fmaxf(fabsf(cr) * 6e-7f, 1e-30f);     // ~5 ulp guard
      const float ang = (fabsf(fd - cr) <= tol) ? fd : cr;
      const float t = ((ang / 6.2831854820251465f) + 0.5f) * 512.0f;
      int b = (int)floorf(t);
      b = b < 0 ? 0 : (b > 511 ? 511 : b);
      (isk ? kb : qb)[(h << 12) + n] = b;
    }
    __syncthreads();
  }
}

__global__ __launch_bounds__(256) void hyp_project_kernel(
    float* __restrict__ Qp, float* __restrict__ Kp)
{
  const int wid  = blockIdx.x * 4 + (threadIdx.x >> 6);
  const int lane = threadIdx.x & 63;
  float* P = (wid < 32768) ? Qp : Kp;
  const int row = wid & 32767;
  float v = P[(row << 6) + lane];
  float ss = v * v;
#pragma unroll
  for (int o = 32; o; o >>= 1) ss += __shfl_xor(ss, o);
  const float nrm = sqrtf(ss);
  const float s = fminf(1.0f, MAX_NORM_F / fmaxf(nrm, 1e-12f));
  P[(row << 6) + lane] = v * s;
}

__global__ __launch_bounds__(256) void cand_kernel(
    const int* __restrict__ qb, const int* __restrict__ kb,
    int* __restrict__ cnt, u16* __restrict__ cand)
{
  const int h = blockIdx.y;
  __shared__ short kbs[N_TOK];
  for (int i = threadIdx.x; i < N_TOK; i += 256)
    kbs[i] = (short)kb[(h << 12) + i];
  __syncthreads();

  const int wave = threadIdx.x >> 6;
  const int lane = threadIdx.x & 63;
  const unsigned long long below = (lane == 63) ? ~0ull >> 1 : ((1ull << lane) - 1);

  for (int t = 0; t < 16; ++t) {
    const int q = blockIdx.x * 64 + wave * 16 + t;
    const int qbv = qb[(h << 12) + q];
    int count = 0;
    for (int base = 0; base < N_TOK && count < CANDN; base += 64) {
      const int d = (int)kbs[base + lane] - qbv;
      const bool match = (d >= -1) && (d <= 1);
      const unsigned long long m = __ballot(match);
      if (match) {
        const int r = count + __popcll(m & below);
        if (r < CANDN) cand[((((h << 12) + q)) << 6) + r] = (u16)(base + lane);
      }
      count += __popcll(m);
    }
    if (lane == 0) cnt[(h << 12) + q] = count < CANDN ? count : CANDN;
  }
}

__global__ __launch_bounds__(256) void attn_kernel(
    const float* __restrict__ Qp, const float* __restrict__ Kp,
    const u16* __restrict__ Vb, const int* __restrict__ cnt,
    const u16* __restrict__ cand, u16* __restrict__ aout)
{
  const int wid  = blockIdx.x * 4 + (threadIdx.x >> 6);
  const int lane = threadIdx.x & 63;
  const int h = wid >> 12;
  const int q = wid & 4095;

  int c = cnt[(h << 12) + q];
  int myc;
  if (c == 0) { myc = lane; c = 64; }
  else myc = (lane < c) ? (int)cand[(((h << 12) + q) << 6) + lane] : 0;

  const float ql = Qp[(((h << 12) + q) << 6) + lane];

  float sc = -INFINITY;
  for (int i = 0; i < c; ++i) {
    const int ci = __shfl(myc, i);
    const float kv = Kp[(((h << 12) + ci) << 6) + lane];
    float p = ql * kv;
#pragma unroll
    for (int o = 32; o; o >>= 1) p += __shfl_xor(p, o);
    if (lane == i) sc = p * ATT_SCALE;
  }

  float m = sc;
#pragma unroll
  for (int o = 32; o; o >>= 1) m = fmaxf(m, __shfl_xor(m, o));
  float p = (lane < c) ? expf(sc - m) : 0.0f;
  float sum = p;
#pragma unroll
  for (int o = 32; o; o >>= 1) sum += __shfl_xor(sum, o);
  const float attn = p / sum;

  float out = 0.0f;
  for (int i = 0; i < c; ++i) {
    const int ci = __shfl(myc, i);
    const float ai = __shfl(attn, i);
    const float vv = bf2f(Vb[(((h << 12) + ci) << 6) + lane]);
    out = fmaf(ai, vv, out);
  }
  aout[q * DMODEL + (h << 6) + lane] = f2bf(out);
}

extern "C" void kernel_launch(void* const* d_in, const int* in_sizes, int n_in,
                              void* d_out, int out_size, void* d_ws, size_t ws_size,
                              hipStream_t stream) {
  const float* query = (const float*)d_in[0];
  const float* key_  = (const float*)d_in[1];
  const float* value = (const float*)d_in[2];
  const float* Wq = (const float*)d_in[3];
  const float* bq = (const float*)d_in[4];
  const float* Wk = (const float*)d_in[5];
  const float* bk = (const float*)d_in[6];
  const float* Wv = (const float*)d_in[7];
  const float* bv = (const float*)d_in[8];
  const float* Wo = (const float*)d_in[9];
  const float* bo = (const float*)d_in[10];

  char* ws = (char*)d_ws;
  float* Qp   = (float*)(ws);                // 8 MB: [h][n][64] f32
  float* Kp   = (float*)(ws + 8388608);      // 8 MB
  u16*   Vb   = (u16*)(ws + 16777216);       // 4 MB: [h][n][64] bf16
  int*   qb   = (int*)(ws + 20971520);       // 128 KB
  int*   kb   = (int*)(ws + 21102592);       // 128 KB
  int*   cnt  = (int*)(ws + 21233664);       // 128 KB
  u16*   cand = (u16*)(ws + 21364736);       // 4 MB
  u16*   aout = (u16*)(ws + 25559040);       // 4 MB
  int*   wl_count = (int*)(ws + 29753344);   // 4 B
  int*   wl   = (int*)(ws + 29753348);       // 32 KB
  // total ~29.79 MB

  wl_init_kernel<<<1, 1, 0, stream>>>(wl_count);
  gemm_qkv_kernel<<<dim3(32, 4, 3), 256, 0, stream>>>(
      query, key_, value, Wq, bq, Wk, bk, Wv, bv, Qp, Kp, Vb);
  bins_pass1_kernel<<<256, 256, 0, stream>>>(query, key_, Wq, Wk, qb, kb, wl_count, wl);
  bins_pass2_kernel<<<128, 64, 0, stream>>>(query, key_, Wq, Wk, qb, kb, wl_count, wl);
  hyp_project_kernel<<<16384, 256, 0, stream>>>(Qp, Kp);
  cand_kernel<<<dim3(64, 8), 256, 0, stream>>>(qb, kb, cnt, cand);
  attn_kernel<<<8192, 256, 0, stream>>>(Qp, Kp, Vb, cnt, cand, aout);
  gemm_out_kernel<<<dim3(32, 4), 256, 0, stream>>>(aout, Wo, bo, (float*)d_out);
}

// Round 6
// 345.710 us; speedup vs baseline: 1.1969x; 1.1969x over previous
//
#include <hip/hip_runtime.h>
#include <math.h>

typedef unsigned short u16;
typedef __attribute__((ext_vector_type(8))) short v8bf;
typedef __attribute__((ext_vector_type(4))) float f32x4;

#define N_TOK 4096
#define DMODEL 512
#define NHEAD 8
#define HDIM 64
#define CANDN 64
#define ATT_SCALE 0.125f
#define MAX_NORM_F 0.99999f
#define WL_CAP 8192

__device__ __forceinline__ float bf2f(u16 u) {
  union { unsigned int i; float f; } v; v.i = ((unsigned int)u) << 16; return v.f;
}
__device__ __forceinline__ u16 f2bf(float f) {
  union { float f; unsigned int i; } v; v.f = f;
  unsigned int x = v.i;
  return (u16)((x + 0x7fffu + ((x >> 16) & 1u)) >> 16);
}
__device__ __forceinline__ uint4 load_pack8(const float* __restrict__ p) {
  const float4 x0 = *(const float4*)p;
  const float4 x1 = *(const float4*)(p + 4);
  union { u16 h[8]; uint4 u; } r;
  r.h[0] = f2bf(x0.x); r.h[1] = f2bf(x0.y); r.h[2] = f2bf(x0.z); r.h[3] = f2bf(x0.w);
  r.h[4] = f2bf(x1.x); r.h[5] = f2bf(x1.y); r.h[6] = f2bf(x1.z); r.h[7] = f2bf(x1.w);
  return r.u;
}

// ---------------------------------------------------------------------------
// GEMM 128x128 tile, BK=32, 4 waves x (4x4) 16x16x32 bf16 MFMAs.
// Poincare projection fused into the epilogue for Q/K (z<2): each wave's
// (i,quad,r) row holds the full 64 head dims across j-regs x 16 lanes, so a
// 4-step shfl_xor over the quad's 16 lanes yields the row norm.
// ---------------------------------------------------------------------------
__global__ __launch_bounds__(256) void gemm_qkv_kernel(
    const float* __restrict__ query, const float* __restrict__ key_, const float* __restrict__ value,
    const float* __restrict__ Wq, const float* __restrict__ bq,
    const float* __restrict__ Wk, const float* __restrict__ bk,
    const float* __restrict__ Wv, const float* __restrict__ bv,
    float* __restrict__ Qp, float* __restrict__ Kp, u16* __restrict__ Vb)
{
  const int z = blockIdx.z;
  const float* A    = (z == 0) ? query : (z == 1) ? key_ : value;
  const float* W    = (z == 0) ? Wq    : (z == 1) ? Wk   : Wv;
  const float* bias = (z == 0) ? bq    : (z == 1) ? bk   : bv;

  __shared__ u16 As[128 * 40];
  __shared__ u16 Ws[128 * 40];

  const int tid  = threadIdx.x;
  const int lane = tid & 63;
  const int wave = tid >> 6;
  const int row4 = tid >> 2;
  const int seg  = tid & 3;

  const int bm = blockIdx.x * 128;
  const int bn = blockIdx.y * 128;
  const int wm = (wave & 1) * 64;
  const int wn = (wave >> 1) * 64;
  const int l15 = lane & 15;
  const int quad = lane >> 4;

  f32x4 acc[4][4] = {};

  for (int kt = 0; kt < DMODEL; kt += 32) {
    uint4 a0 = load_pack8(A + (bm + row4) * DMODEL + kt + seg * 8);
    uint4 a1 = load_pack8(A + (bm + row4 + 64) * DMODEL + kt + seg * 8);
    uint4 w0 = load_pack8(W + (bn + row4) * DMODEL + kt + seg * 8);
    uint4 w1 = load_pack8(W + (bn + row4 + 64) * DMODEL + kt + seg * 8);
    __syncthreads();
    *(uint4*)&As[row4 * 40 + seg * 8] = a0;
    *(uint4*)&As[(row4 + 64) * 40 + seg * 8] = a1;
    *(uint4*)&Ws[row4 * 40 + seg * 8] = w0;
    *(uint4*)&Ws[(row4 + 64) * 40 + seg * 8] = w1;
    __syncthreads();
    v8bf af[4], bfr[4];
#pragma unroll
    for (int i = 0; i < 4; ++i)
      af[i] = *(const v8bf*)&As[(wm + i * 16 + l15) * 40 + quad * 8];
#pragma unroll
    for (int j = 0; j < 4; ++j)
      bfr[j] = *(const v8bf*)&Ws[(wn + j * 16 + l15) * 40 + quad * 8];
#pragma unroll
    for (int i = 0; i < 4; ++i)
#pragma unroll
      for (int j = 0; j < 4; ++j)
        acc[i][j] = __builtin_amdgcn_mfma_f32_16x16x32_bf16(af[i], bfr[j], acc[i][j], 0, 0, 0);
  }

  float bval[4];
#pragma unroll
  for (int j = 0; j < 4; ++j) bval[j] = bias[bn + wn + j * 16 + l15];
  const int h = (bn + wn) >> 6;  // wave covers exactly one 64-col head

#pragma unroll
  for (int i = 0; i < 4; ++i) {
#pragma unroll
    for (int r = 0; r < 4; ++r) {
      const int row = bm + wm + i * 16 + quad * 4 + r;
      float v0 = acc[i][0][r] + bval[0];
      float v1 = acc[i][1][r] + bval[1];
      float v2 = acc[i][2][r] + bval[2];
      float v3 = acc[i][3][r] + bval[3];
      if (z != 2) {  // hyperbolic clip fused (row norm over 64 dims)
        float ss = v0 * v0 + v1 * v1 + v2 * v2 + v3 * v3;
#pragma unroll
        for (int o = 1; o < 16; o <<= 1) ss += __shfl_xor(ss, o);
        const float s = fminf(1.0f, MAX_NORM_F / fmaxf(sqrtf(ss), 1e-12f));
        v0 *= s; v1 *= s; v2 *= s; v3 *= s;
      }
      const int base = (((h << 12) + row) << 6) + l15;
      if (z == 2) {
        Vb[base +  0] = f2bf(v0); Vb[base + 16] = f2bf(v1);
        Vb[base + 32] = f2bf(v2); Vb[base + 48] = f2bf(v3);
      } else {
        float* P = z ? Kp : Qp;
        P[base +  0] = v0; P[base + 16] = v1;
        P[base + 32] = v2; P[base + 48] = v3;
      }
    }
  }
}

__global__ __launch_bounds__(256) void gemm_out_kernel(
    const u16* __restrict__ A, const float* __restrict__ W,
    const float* __restrict__ bias, float* __restrict__ O)
{
  __shared__ u16 As[128 * 40];
  __shared__ u16 Ws[128 * 40];

  const int tid  = threadIdx.x;
  const int lane = tid & 63;
  const int wave = tid >> 6;
  const int row4 = tid >> 2;
  const int seg  = tid & 3;

  const int bm = blockIdx.x * 128;
  const int bn = blockIdx.y * 128;
  const int wm = (wave & 1) * 64;
  const int wn = (wave >> 1) * 64;
  const int l15 = lane & 15;
  const int quad = lane >> 4;

  f32x4 acc[4][4] = {};

  for (int kt = 0; kt < DMODEL; kt += 32) {
    uint4 a0 = *(const uint4*)(A + (bm + row4) * DMODEL + kt + seg * 8);
    uint4 a1 = *(const uint4*)(A + (bm + row4 + 64) * DMODEL + kt + seg * 8);
    uint4 w0 = load_pack8(W + (bn + row4) * DMODEL + kt + seg * 8);
    uint4 w1 = load_pack8(W + (bn + row4 + 64) * DMODEL + kt + seg * 8);
    __syncthreads();
    *(uint4*)&As[row4 * 40 + seg * 8] = a0;
    *(uint4*)&As[(row4 + 64) * 40 + seg * 8] = a1;
    *(uint4*)&Ws[row4 * 40 + seg * 8] = w0;
    *(uint4*)&Ws[(row4 + 64) * 40 + seg * 8] = w1;
    __syncthreads();
    v8bf af[4], bfr[4];
#pragma unroll
    for (int i = 0; i < 4; ++i)
      af[i] = *(const v8bf*)&As[(wm + i * 16 + l15) * 40 + quad * 8];
#pragma unroll
    for (int j = 0; j < 4; ++j)
      bfr[j] = *(const v8bf*)&Ws[(wn + j * 16 + l15) * 40 + quad * 8];
#pragma unroll
    for (int i = 0; i < 4; ++i)
#pragma unroll
      for (int j = 0; j < 4; ++j)
        acc[i][j] = __builtin_amdgcn_mfma_f32_16x16x32_bf16(af[i], bfr[j], acc[i][j], 0, 0, 0);
  }

#pragma unroll
  for (int j = 0; j < 4; ++j) {
    const int cg = bn + wn + j * 16 + l15;
    const float bval = bias[cg];
#pragma unroll
    for (int i = 0; i < 4; ++i) {
      const int rbase = bm + wm + i * 16 + quad * 4;
#pragma unroll
      for (int r = 0; r < 4; ++r)
        O[(rbase + r) * DMODEL + cg] = acc[i][j][r] + bval;
    }
  }
}

// ---------------------------------------------------------------------------
// Bins: pass 1 f64 + boundary flagging; pass 2 bit-mimics np-f32 for flagged
// elements (sequential-FMA f32 dots, numpy pairwise-8 norm, fdlibm atan2f
// guarded by correctly-rounded f64 atan2). Unchanged semantics from R5 (which
// passed); pass 2 restructured for latency: 16-wide batched float4 loads
// (FMA order preserved) and shuffle-based norm gather (order preserved).
// ---------------------------------------------------------------------------

__global__ void wl_init_kernel(int* __restrict__ wl_count) { *wl_count = 0; }

__global__ __launch_bounds__(256) void bins_pass1_kernel(
    const float* __restrict__ query, const float* __restrict__ key_,
    const float* __restrict__ Wq, const float* __restrict__ Wk,
    int* __restrict__ qb, int* __restrict__ kb,
    int* __restrict__ wl_count, int* __restrict__ wl)
{
  const int tid = blockIdx.x * 256 + threadIdx.x;  // 0..65535
  const int n   = tid & 4095;
  const int h   = (tid >> 12) & 7;
  const int isk = tid >> 15;
  const float* X = isk ? key_ : query;
  const float* W = isk ? Wk : Wq;
  const float* xr = X + n * DMODEL;
  const float* w0 = W + (h * 64 + 0) * DMODEL;
  const float* w1 = W + (h * 64 + 1) * DMODEL;
  double a0 = 0.0, a1 = 0.0;  // biases are zero
  for (int c = 0; c < DMODEL; c += 4) {
    const float4 x = *(const float4*)(xr + c);
    const float4 u = *(const float4*)(w0 + c);
    const float4 v = *(const float4*)(w1 + c);
    a0 += (double)x.x * u.x; a1 += (double)x.x * v.x;
    a0 += (double)x.y * u.y; a1 += (double)x.y * v.y;
    a0 += (double)x.z * u.z; a1 += (double)x.z * v.z;
    a0 += (double)x.w * u.w; a1 += (double)x.w * v.w;
  }
  double ang = atan2(a1, a0);
  double t = (ang / 6.283185307179586 + 0.5) * 512.0;
  int b = (int)floor(t);
  b = b < 0 ? 0 : (b > 511 ? 511 : b);
  (isk ? kb : qb)[(h << 12) + n] = b;

  const double r = sqrt(a0 * a0 + a1 * a1);
  const double dist = fabs(t - nearbyint(t));
  const double margin = fmin(0.45, 3.3e-4 / fmax(r, 1e-30) + 5e-5);
  if (dist < margin) {
    int idx = atomicAdd(wl_count, 1);
    if (idx < WL_CAP) wl[idx] = (isk << 15) | (h << 12) | n;
  }
}

__device__ float fdlibm_atanf(float x) {
#pragma clang fp contract(off)
  const float atanhi[4] = {4.6364760399e-01f, 7.8539812565e-01f,
                           9.8279368877e-01f, 1.5707962513e+00f};
  const float atanlo[4] = {5.0121582440e-09f, 3.7748947079e-08f,
                           3.4473217170e-08f, 7.5497894159e-08f};
  const float aT[5] = {3.3333328366e-01f, -1.9999158382e-01f, 1.4253635705e-01f,
                       -1.0648017377e-01f, 6.1687607318e-02f};
  unsigned ix = __float_as_uint(x);
  const unsigned sign = ix >> 31;
  ix &= 0x7fffffffu;
  int id;
  float z, w, s1, s2;
  if (ix >= 0x4c800000u) {
    z = atanhi[3] + 0x1p-120f;
    return sign ? -z : z;
  }
  if (ix < 0x3ee00000u) {
    if (ix < 0x39800000u) return x;
    id = -1;
  } else {
    x = fabsf(x);
    if (ix < 0x3f980000u) {
      if (ix < 0x3f300000u) { id = 0; x = (2.0f * x - 1.0f) / (2.0f + x); }
      else                  { id = 1; x = (x - 1.0f) / (x + 1.0f); }
    } else {
      if (ix < 0x401c0000u) { id = 2; x = (x - 1.5f) / (1.0f + 1.5f * x); }
      else                  { id = 3; x = -1.0f / x; }
    }
  }
  z = x * x;
  w = z * z;
  s1 = z * (aT[0] + w * (aT[2] + w * aT[4]));
  s2 = w * (aT[1] + w * aT[3]);
  if (id < 0) return x - x * (s1 + s2);
  z = atanhi[id] - ((x * (s1 + s2) - atanlo[id]) - x);
  return sign ? -z : z;
}

__device__ float fdlibm_atan2f(float y, float x) {
#pragma clang fp contract(off)
  const float pi = 3.1415927410e+00f, pi_lo = -8.7422776573e-08f;
  const unsigned hx = __float_as_uint(x), hy = __float_as_uint(y);
  if (hx == 0x3f800000u) return fdlibm_atanf(y);
  const unsigned m = ((hy >> 31) & 1u) | ((hx >> 30) & 2u);
  const unsigned ix = hx & 0x7fffffffu, iy = hy & 0x7fffffffu;
  if (iy == 0u) {
    switch (m) { case 0: case 1: return y; case 2: return pi; default: return -pi; }
  }
  if (ix == 0u) return (m & 1u) ? -1.57079637050628662f : 1.57079637050628662f;
  float z;
  if (ix + (26u << 23) < iy) {
    z = 1.57079637050628662f;
    return (m & 1u) ? -z : z;
  }
  if ((m & 2u) && iy + (26u << 23) < ix) z = 0.0f;
  else z = fdlibm_atanf(fabsf(y / x));
  switch (m) {
    case 0: return z;
    case 1: return -z;
    case 2: return pi - (z - pi_lo);
    default: return (z - pi_lo) - pi;
  }
}

__global__ __launch_bounds__(256) void bins_pass2_kernel(
    const float* __restrict__ query, const float* __restrict__ key_,
    const float* __restrict__ Wq, const float* __restrict__ Wk,
    int* __restrict__ qb, int* __restrict__ kb,
    const int* __restrict__ wl_count, const int* __restrict__ wl)
{
  int cnt_ = *wl_count;
  if (cnt_ > WL_CAP) cnt_ = WL_CAP;
  const int w = threadIdx.x >> 6;
  const int d = threadIdx.x & 63;
  for (int e = blockIdx.x * 4 + w; e < cnt_; e += gridDim.x * 4) {
    const int code = wl[e];
    const int n = code & 4095;
    const int h = (code >> 12) & 7;
    const int isk = (code >> 15) & 1;
    const float* xr = (isk ? key_ : query) + n * DMODEL;
    const float* wr = (isk ? Wk : Wq) + (h * 64 + d) * DMODEL;
    // sequential f32 FMA chain, k ascending; loads batched 16-wide (order of
    // the FMA chain — the part that determines rounding — is unchanged)
    float acc = 0.0f;
    for (int k = 0; k < DMODEL; k += 16) {
      const float4 xa = *(const float4*)(xr + k);
      const float4 xb = *(const float4*)(xr + k + 4);
      const float4 xc = *(const float4*)(xr + k + 8);
      const float4 xd = *(const float4*)(xr + k + 12);
      const float4 wa = *(const float4*)(wr + k);
      const float4 wb = *(const float4*)(wr + k + 4);
      const float4 wc = *(const float4*)(wr + k + 8);
      const float4 wd = *(const float4*)(wr + k + 12);
      acc = __fmaf_rn(xa.x, wa.x, acc); acc = __fmaf_rn(xa.y, wa.y, acc);
      acc = __fmaf_rn(xa.z, wa.z, acc); acc = __fmaf_rn(xa.w, wa.w, acc);
      acc = __fmaf_rn(xb.x, wb.x, acc); acc = __fmaf_rn(xb.y, wb.y, acc);
      acc = __fmaf_rn(xb.z, wb.z, acc); acc = __fmaf_rn(xb.w, wb.w, acc);
      acc = __fmaf_rn(xc.x, wc.x, acc); acc = __fmaf_rn(xc.y, wc.y, acc);
      acc = __fmaf_rn(xc.z, wc.z, acc); acc = __fmaf_rn(xc.w, wc.w, acc);
      acc = __fmaf_rn(xd.x, wd.x, acc); acc = __fmaf_rn(xd.y, wd.y, acc);
      acc = __fmaf_rn(xd.z, wd.z, acc); acc = __fmaf_rn(xd.w, wd.w, acc);
    }
    {
#pragma clang fp contract(off)
      const float sq = acc * acc;
      // numpy pairwise n=64 scalar path: 8 accumulators, stride-8, then tree.
      // Gathered via shuffles in the exact same addition order as before.
      float rr[8];
#pragma unroll
      for (int j = 0; j < 8; ++j) rr[j] = __shfl(sq, j);
      for (int i = 8; i < 64; i += 8) {
#pragma unroll
        for (int j = 0; j < 8; ++j) rr[j] += __shfl(sq, i + j);
      }
      const float ss = ((rr[0] + rr[1]) + (rr[2] + rr[3])) +
                       ((rr[4] + rr[5]) + (rr[6] + rr[7]));
      const float nrm = __fsqrt_rn(ss);
      const float s = fminf(1.0f, 0.99999f / fmaxf(nrm, 1e-12f));
      const float c0 = __shfl(acc, 0) * s;
      const float c1 = __shfl(acc, 1) * s;
      const float cr = (float)atan2((double)c1, (double)c0);  // CR fallback
      const float fd = fdlibm_atan2f(c1, c0);
      const float tol = fmaxf(fabsf(cr) * 6e-7f, 1e-30f);     // ~5 ulp guard
      const float ang = (fabsf(fd - cr) <= tol) ? fd : cr;
      const float t = ((ang / 6.2831854820251465f) + 0.5f) * 512.0f;
      int b = (int)floorf(t);
      b = b < 0 ? 0 : (b > 511 ? 511 : b);
      if (d == 0) (isk ? kb : qb)[(h << 12) + n] = b;
    }
  }
}

__global__ __launch_bounds__(256) void cand_kernel(
    const int* __restrict__ qb, const int* __restrict__ kb,
    int* __restrict__ cnt, u16* __restrict__ cand)
{
  const int h = blockIdx.y;
  __shared__ short kbs[N_TOK];
  for (int i = threadIdx.x; i < N_TOK; i += 256)
    kbs[i] = (short)kb[(h << 12) + i];
  __syncthreads();

  const int wave = threadIdx.x >> 6;
  const int lane = threadIdx.x & 63;
  const unsigned long long below = (lane == 63) ? ~0ull >> 1 : ((1ull << lane) - 1);

  for (int t = 0; t < 16; ++t) {
    const int q = blockIdx.x * 64 + wave * 16 + t;
    const int qbv = qb[(h << 12) + q];
    int count = 0;
    for (int base = 0; base < N_TOK && count < CANDN; base += 64) {
      const int d = (int)kbs[base + lane] - qbv;
      const bool match = (d >= -1) && (d <= 1);
      const unsigned long long m = __ballot(match);
      if (match) {
        const int r = count + __popcll(m & below);
        if (r < CANDN) cand[((((h << 12) + q)) << 6) + r] = (u16)(base + lane);
      }
      count += __popcll(m);
    }
    if (lane == 0) cnt[(h << 12) + q] = count < CANDN ? count : CANDN;
  }
}

// ---------------------------------------------------------------------------
// Attention, restructured (R5 post-mortem: serial shuffle-reduce chains made
// it latency-bound at 34% VALUBusy). Phase 1: lane = candidate, each lane
// computes its full 64-FMA dot (Q broadcast from LDS, K via float4 row
// stream) — no shuffles in the loop. One 12-shuffle softmax. LDS transpose
// of (attn, cand). Phase 2: lane = dim, broadcast weights, coalesced V rows.
// ---------------------------------------------------------------------------
__global__ __launch_bounds__(256) void attn_kernel(
    const float* __restrict__ Qp, const float* __restrict__ Kp,
    const u16* __restrict__ Vb, const int* __restrict__ cnt,
    const u16* __restrict__ cand, u16* __restrict__ aout)
{
  __shared__ float s_q[4][64];
  __shared__ float s_attn[4][64];
  __shared__ int   s_ci[4][64];

  const int w    = threadIdx.x >> 6;
  const int lane = threadIdx.x & 63;
  const int wid  = blockIdx.x * 4 + w;  // 0..32767
  const int h = wid >> 12;
  const int q = wid & 4095;
  const int hq = (h << 12) + q;

  int c = cnt[hq];
  int myc;
  if (c == 0) { myc = lane; c = 64; }
  else myc = (lane < c) ? (int)cand[(hq << 6) + lane] : 0;

  s_q[w][lane] = Qp[(hq << 6) + lane];
  s_ci[w][lane] = myc;
  __syncthreads();

  // Phase 1: lane = candidate
  const float* krow = Kp + (((h << 12) + myc) << 6);
  float sc = 0.0f;
#pragma unroll
  for (int d = 0; d < HDIM; d += 4) {
    const float4 kv = *(const float4*)(krow + d);
    sc = fmaf(s_q[w][d + 0], kv.x, sc);
    sc = fmaf(s_q[w][d + 1], kv.y, sc);
    sc = fmaf(s_q[w][d + 2], kv.z, sc);
    sc = fmaf(s_q[w][d + 3], kv.w, sc);
  }
  sc = (lane < c) ? sc * ATT_SCALE : -INFINITY;

  float m = sc;
#pragma unroll
  for (int o = 32; o; o >>= 1) m = fmaxf(m, __shfl_xor(m, o));
  float p = (lane < c) ? expf(sc - m) : 0.0f;
  float sum = p;
#pragma unroll
  for (int o = 32; o; o >>= 1) sum += __shfl_xor(sum, o);
  s_attn[w][lane] = p / sum;
  __syncthreads();

  // Phase 2: lane = dim
  const u16* vbase = Vb + (h << 18);
  float out = 0.0f;
  for (int i = 0; i < c; ++i) {
    const float ai = s_attn[w][i];
    const int ci = s_ci[w][i];
    out = fmaf(ai, bf2f(vbase[(ci << 6) + lane]), out);
  }
  aout[q * DMODEL + (h << 6) + lane] = f2bf(out);
}

extern "C" void kernel_launch(void* const* d_in, const int* in_sizes, int n_in,
                              void* d_out, int out_size, void* d_ws, size_t ws_size,
                              hipStream_t stream) {
  const float* query = (const float*)d_in[0];
  const float* key_  = (const float*)d_in[1];
  const float* value = (const float*)d_in[2];
  const float* Wq = (const float*)d_in[3];
  const float* bq = (const float*)d_in[4];
  const float* Wk = (const float*)d_in[5];
  const float* bk = (const float*)d_in[6];
  const float* Wv = (const float*)d_in[7];
  const float* bv = (const float*)d_in[8];
  const float* Wo = (const float*)d_in[9];
  const float* bo = (const float*)d_in[10];

  char* ws = (char*)d_ws;
  float* Qp   = (float*)(ws);                // 8 MB: [h][n][64] f32 (projected)
  float* Kp   = (float*)(ws + 8388608);      // 8 MB (projected)
  u16*   Vb   = (u16*)(ws + 16777216);       // 4 MB: [h][n][64] bf16
  int*   qb   = (int*)(ws + 20971520);       // 128 KB
  int*   kb   = (int*)(ws + 21102592);       // 128 KB
  int*   cnt  = (int*)(ws + 21233664);       // 128 KB
  u16*   cand = (u16*)(ws + 21364736);       // 4 MB
  u16*   aout = (u16*)(ws + 25559040);       // 4 MB
  int*   wl_count = (int*)(ws + 29753344);   // 4 B
  int*   wl   = (int*)(ws + 29753348);       // 32 KB

  wl_init_kernel<<<1, 1, 0, stream>>>(wl_count);
  gemm_qkv_kernel<<<dim3(32, 4, 3), 256, 0, stream>>>(
      query, key_, value, Wq, bq, Wk, bk, Wv, bv, Qp, Kp, Vb);
  bins_pass1_kernel<<<256, 256, 0, stream>>>(query, key_, Wq, Wk, qb, kb, wl_count, wl);
  bins_pass2_kernel<<<64, 256, 0, stream>>>(query, key_, Wq, Wk, qb, kb, wl_count, wl);
  cand_kernel<<<dim3(64, 8), 256, 0, stream>>>(qb, kb, cnt, cand);
  attn_kernel<<<8192, 256, 0, stream>>>(Qp, Kp, Vb, cnt, cand, aout);
  gemm_out_kernel<<<dim3(32, 4), 256, 0, stream>>>(aout, Wo, bo, (float*)d_out);
}

// Round 7
// 273.304 us; speedup vs baseline: 1.5140x; 1.2649x over previous
//
#include <hip/hip_runtime.h>
#include <math.h>

typedef unsigned short u16;
typedef __attribute__((ext_vector_type(8))) short v8bf;
typedef __attribute__((ext_vector_type(4))) float f32x4;

#define N_TOK 4096
#define DMODEL 512
#define NHEAD 8
#define HDIM 64
#define CANDN 64
#define NBINS 512
#define BINCAP 64
#define ATT_SCALE 0.125f
#define MAX_NORM_F 0.99999f
#define WL_CAP 8192

__device__ __forceinline__ float bf2f(u16 u) {
  union { unsigned int i; float f; } v; v.i = ((unsigned int)u) << 16; return v.f;
}
__device__ __forceinline__ u16 f2bf(float f) {
  union { float f; unsigned int i; } v; v.f = f;
  unsigned int x = v.i;
  return (u16)((x + 0x7fffu + ((x >> 16) & 1u)) >> 16);
}
__device__ __forceinline__ uint4 load_pack8(const float* __restrict__ p) {
  const float4 x0 = *(const float4*)p;
  const float4 x1 = *(const float4*)(p + 4);
  union { u16 h[8]; uint4 u; } r;
  r.h[0] = f2bf(x0.x); r.h[1] = f2bf(x0.y); r.h[2] = f2bf(x0.z); r.h[3] = f2bf(x0.w);
  r.h[4] = f2bf(x1.x); r.h[5] = f2bf(x1.y); r.h[6] = f2bf(x1.z); r.h[7] = f2bf(x1.w);
  return r.u;
}

// ---------------------------------------------------------------------------
// GEMM 128x128 tile, BK=32, 4 waves x (4x4) 16x16x32 bf16 MFMAs.
// Poincare projection fused into Q/K epilogue (quad-group shfl_xor norm).
// ---------------------------------------------------------------------------
__global__ __launch_bounds__(256) void gemm_qkv_kernel(
    const float* __restrict__ query, const float* __restrict__ key_, const float* __restrict__ value,
    const float* __restrict__ Wq, const float* __restrict__ bq,
    const float* __restrict__ Wk, const float* __restrict__ bk,
    const float* __restrict__ Wv, const float* __restrict__ bv,
    float* __restrict__ Qp, float* __restrict__ Kp, u16* __restrict__ Vb)
{
  const int z = blockIdx.z;
  const float* A    = (z == 0) ? query : (z == 1) ? key_ : value;
  const float* W    = (z == 0) ? Wq    : (z == 1) ? Wk   : Wv;
  const float* bias = (z == 0) ? bq    : (z == 1) ? bk   : bv;

  __shared__ u16 As[128 * 40];
  __shared__ u16 Ws[128 * 40];

  const int tid  = threadIdx.x;
  const int lane = tid & 63;
  const int wave = tid >> 6;
  const int row4 = tid >> 2;
  const int seg  = tid & 3;

  const int bm = blockIdx.x * 128;
  const int bn = blockIdx.y * 128;
  const int wm = (wave & 1) * 64;
  const int wn = (wave >> 1) * 64;
  const int l15 = lane & 15;
  const int quad = lane >> 4;

  f32x4 acc[4][4] = {};

  for (int kt = 0; kt < DMODEL; kt += 32) {
    uint4 a0 = load_pack8(A + (bm + row4) * DMODEL + kt + seg * 8);
    uint4 a1 = load_pack8(A + (bm + row4 + 64) * DMODEL + kt + seg * 8);
    uint4 w0 = load_pack8(W + (bn + row4) * DMODEL + kt + seg * 8);
    uint4 w1 = load_pack8(W + (bn + row4 + 64) * DMODEL + kt + seg * 8);
    __syncthreads();
    *(uint4*)&As[row4 * 40 + seg * 8] = a0;
    *(uint4*)&As[(row4 + 64) * 40 + seg * 8] = a1;
    *(uint4*)&Ws[row4 * 40 + seg * 8] = w0;
    *(uint4*)&Ws[(row4 + 64) * 40 + seg * 8] = w1;
    __syncthreads();
    v8bf af[4], bfr[4];
#pragma unroll
    for (int i = 0; i < 4; ++i)
      af[i] = *(const v8bf*)&As[(wm + i * 16 + l15) * 40 + quad * 8];
#pragma unroll
    for (int j = 0; j < 4; ++j)
      bfr[j] = *(const v8bf*)&Ws[(wn + j * 16 + l15) * 40 + quad * 8];
#pragma unroll
    for (int i = 0; i < 4; ++i)
#pragma unroll
      for (int j = 0; j < 4; ++j)
        acc[i][j] = __builtin_amdgcn_mfma_f32_16x16x32_bf16(af[i], bfr[j], acc[i][j], 0, 0, 0);
  }

  float bval[4];
#pragma unroll
  for (int j = 0; j < 4; ++j) bval[j] = bias[bn + wn + j * 16 + l15];
  const int h = (bn + wn) >> 6;

#pragma unroll
  for (int i = 0; i < 4; ++i) {
#pragma unroll
    for (int r = 0; r < 4; ++r) {
      const int row = bm + wm + i * 16 + quad * 4 + r;
      float v0 = acc[i][0][r] + bval[0];
      float v1 = acc[i][1][r] + bval[1];
      float v2 = acc[i][2][r] + bval[2];
      float v3 = acc[i][3][r] + bval[3];
      if (z != 2) {
        float ss = v0 * v0 + v1 * v1 + v2 * v2 + v3 * v3;
#pragma unroll
        for (int o = 1; o < 16; o <<= 1) ss += __shfl_xor(ss, o);
        const float s = fminf(1.0f, MAX_NORM_F / fmaxf(sqrtf(ss), 1e-12f));
        v0 *= s; v1 *= s; v2 *= s; v3 *= s;
      }
      const int base = (((h << 12) + row) << 6) + l15;
      if (z == 2) {
        Vb[base +  0] = f2bf(v0); Vb[base + 16] = f2bf(v1);
        Vb[base + 32] = f2bf(v2); Vb[base + 48] = f2bf(v3);
      } else {
        float* P = z ? Kp : Qp;
        P[base +  0] = v0; P[base + 16] = v1;
        P[base + 32] = v2; P[base + 48] = v3;
      }
    }
  }
}

__global__ __launch_bounds__(256) void gemm_out_kernel(
    const u16* __restrict__ A, const float* __restrict__ W,
    const float* __restrict__ bias, float* __restrict__ O)
{
  __shared__ u16 As[128 * 40];
  __shared__ u16 Ws[128 * 40];

  const int tid  = threadIdx.x;
  const int lane = tid & 63;
  const int wave = tid >> 6;
  const int row4 = tid >> 2;
  const int seg  = tid & 3;

  const int bm = blockIdx.x * 128;
  const int bn = blockIdx.y * 128;
  const int wm = (wave & 1) * 64;
  const int wn = (wave >> 1) * 64;
  const int l15 = lane & 15;
  const int quad = lane >> 4;

  f32x4 acc[4][4] = {};

  for (int kt = 0; kt < DMODEL; kt += 32) {
    uint4 a0 = *(const uint4*)(A + (bm + row4) * DMODEL + kt + seg * 8);
    uint4 a1 = *(const uint4*)(A + (bm + row4 + 64) * DMODEL + kt + seg * 8);
    uint4 w0 = load_pack8(W + (bn + row4) * DMODEL + kt + seg * 8);
    uint4 w1 = load_pack8(W + (bn + row4 + 64) * DMODEL + kt + seg * 8);
    __syncthreads();
    *(uint4*)&As[row4 * 40 + seg * 8] = a0;
    *(uint4*)&As[(row4 + 64) * 40 + seg * 8] = a1;
    *(uint4*)&Ws[row4 * 40 + seg * 8] = w0;
    *(uint4*)&Ws[(row4 + 64) * 40 + seg * 8] = w1;
    __syncthreads();
    v8bf af[4], bfr[4];
#pragma unroll
    for (int i = 0; i < 4; ++i)
      af[i] = *(const v8bf*)&As[(wm + i * 16 + l15) * 40 + quad * 8];
#pragma unroll
    for (int j = 0; j < 4; ++j)
      bfr[j] = *(const v8bf*)&Ws[(wn + j * 16 + l15) * 40 + quad * 8];
#pragma unroll
    for (int i = 0; i < 4; ++i)
#pragma unroll
      for (int j = 0; j < 4; ++j)
        acc[i][j] = __builtin_amdgcn_mfma_f32_16x16x32_bf16(af[i], bfr[j], acc[i][j], 0, 0, 0);
  }

#pragma unroll
  for (int j = 0; j < 4; ++j) {
    const int cg = bn + wn + j * 16 + l15;
    const float bval = bias[cg];
#pragma unroll
    for (int i = 0; i < 4; ++i) {
      const int rbase = bm + wm + i * 16 + quad * 4;
#pragma unroll
      for (int r = 0; r < 4; ++r)
        O[(rbase + r) * DMODEL + cg] = acc[i][j][r] + bval;
    }
  }
}

// ---------------------------------------------------------------------------
// Bins: pass 1 f64 + boundary flagging; pass 2 np-f32 bit-mimic for flagged
// elements (R5-verified semantics, unchanged).
// ---------------------------------------------------------------------------
__global__ void wl_init_kernel(int* __restrict__ wl_count) { *wl_count = 0; }

__global__ __launch_bounds__(256) void bins_pass1_kernel(
    const float* __restrict__ query, const float* __restrict__ key_,
    const float* __restrict__ Wq, const float* __restrict__ Wk,
    int* __restrict__ qb, int* __restrict__ kb,
    int* __restrict__ wl_count, int* __restrict__ wl)
{
  const int tid = blockIdx.x * 256 + threadIdx.x;
  const int n   = tid & 4095;
  const int h   = (tid >> 12) & 7;
  const int isk = tid >> 15;
  const float* X = isk ? key_ : query;
  const float* W = isk ? Wk : Wq;
  const float* xr = X + n * DMODEL;
  const float* w0 = W + (h * 64 + 0) * DMODEL;
  const float* w1 = W + (h * 64 + 1) * DMODEL;
  double a0 = 0.0, a1 = 0.0;
  for (int c = 0; c < DMODEL; c += 4) {
    const float4 x = *(const float4*)(xr + c);
    const float4 u = *(const float4*)(w0 + c);
    const float4 v = *(const float4*)(w1 + c);
    a0 += (double)x.x * u.x; a1 += (double)x.x * v.x;
    a0 += (double)x.y * u.y; a1 += (double)x.y * v.y;
    a0 += (double)x.z * u.z; a1 += (double)x.z * v.z;
    a0 += (double)x.w * u.w; a1 += (double)x.w * v.w;
  }
  double ang = atan2(a1, a0);
  double t = (ang / 6.283185307179586 + 0.5) * 512.0;
  int b = (int)floor(t);
  b = b < 0 ? 0 : (b > 511 ? 511 : b);
  (isk ? kb : qb)[(h << 12) + n] = b;

  const double r = sqrt(a0 * a0 + a1 * a1);
  const double dist = fabs(t - nearbyint(t));
  const double margin = fmin(0.45, 3.3e-4 / fmax(r, 1e-30) + 5e-5);
  if (dist < margin) {
    int idx = atomicAdd(wl_count, 1);
    if (idx < WL_CAP) wl[idx] = (isk << 15) | (h << 12) | n;
  }
}

__device__ float fdlibm_atanf(float x) {
#pragma clang fp contract(off)
  const float atanhi[4] = {4.6364760399e-01f, 7.8539812565e-01f,
                           9.8279368877e-01f, 1.5707962513e+00f};
  const float atanlo[4] = {5.0121582440e-09f, 3.7748947079e-08f,
                           3.4473217170e-08f, 7.5497894159e-08f};
  const float aT[5] = {3.3333328366e-01f, -1.9999158382e-01f, 1.4253635705e-01f,
                       -1.0648017377e-01f, 6.1687607318e-02f};
  unsigned ix = __float_as_uint(x);
  const unsigned sign = ix >> 31;
  ix &= 0x7fffffffu;
  int id;
  float z, w, s1, s2;
  if (ix >= 0x4c800000u) {
    z = atanhi[3] + 0x1p-120f;
    return sign ? -z : z;
  }
  if (ix < 0x3ee00000u) {
    if (ix < 0x39800000u) return x;
    id = -1;
  } else {
    x = fabsf(x);
    if (ix < 0x3f980000u) {
      if (ix < 0x3f300000u) { id = 0; x = (2.0f * x - 1.0f) / (2.0f + x); }
      else                  { id = 1; x = (x - 1.0f) / (x + 1.0f); }
    } else {
      if (ix < 0x401c0000u) { id = 2; x = (x - 1.5f) / (1.0f + 1.5f * x); }
      else                  { id = 3; x = -1.0f / x; }
    }
  }
  z = x * x;
  w = z * z;
  s1 = z * (aT[0] + w * (aT[2] + w * aT[4]));
  s2 = w * (aT[1] + w * aT[3]);
  if (id < 0) return x - x * (s1 + s2);
  z = atanhi[id] - ((x * (s1 + s2) - atanlo[id]) - x);
  return sign ? -z : z;
}

__device__ float fdlibm_atan2f(float y, float x) {
#pragma clang fp contract(off)
  const float pi = 3.1415927410e+00f, pi_lo = -8.7422776573e-08f;
  const unsigned hx = __float_as_uint(x), hy = __float_as_uint(y);
  if (hx == 0x3f800000u) return fdlibm_atanf(y);
  const unsigned m = ((hy >> 31) & 1u) | ((hx >> 30) & 2u);
  const unsigned ix = hx & 0x7fffffffu, iy = hy & 0x7fffffffu;
  if (iy == 0u) {
    switch (m) { case 0: case 1: return y; case 2: return pi; default: return -pi; }
  }
  if (ix == 0u) return (m & 1u) ? -1.57079637050628662f : 1.57079637050628662f;
  float z;
  if (ix + (26u << 23) < iy) {
    z = 1.57079637050628662f;
    return (m & 1u) ? -z : z;
  }
  if ((m & 2u) && iy + (26u << 23) < ix) z = 0.0f;
  else z = fdlibm_atanf(fabsf(y / x));
  switch (m) {
    case 0: return z;
    case 1: return -z;
    case 2: return pi - (z - pi_lo);
    default: return (z - pi_lo) - pi;
  }
}

__global__ __launch_bounds__(256) void bins_pass2_kernel(
    const float* __restrict__ query, const float* __restrict__ key_,
    const float* __restrict__ Wq, const float* __restrict__ Wk,
    int* __restrict__ qb, int* __restrict__ kb,
    const int* __restrict__ wl_count, const int* __restrict__ wl)
{
  int cnt_ = *wl_count;
  if (cnt_ > WL_CAP) cnt_ = WL_CAP;
  const int w = threadIdx.x >> 6;
  const int d = threadIdx.x & 63;
  for (int e = blockIdx.x * 4 + w; e < cnt_; e += gridDim.x * 4) {
    const int code = wl[e];
    const int n = code & 4095;
    const int h = (code >> 12) & 7;
    const int isk = (code >> 15) & 1;
    const float* xr = (isk ? key_ : query) + n * DMODEL;
    const float* wr = (isk ? Wk : Wq) + (h * 64 + d) * DMODEL;
    float acc = 0.0f;
    for (int k = 0; k < DMODEL; k += 16) {
      const float4 xa = *(const float4*)(xr + k);
      const float4 xb = *(const float4*)(xr + k + 4);
      const float4 xc = *(const float4*)(xr + k + 8);
      const float4 xd = *(const float4*)(xr + k + 12);
      const float4 wa = *(const float4*)(wr + k);
      const float4 wb = *(const float4*)(wr + k + 4);
      const float4 wc = *(const float4*)(wr + k + 8);
      const float4 wd = *(const float4*)(wr + k + 12);
      acc = __fmaf_rn(xa.x, wa.x, acc); acc = __fmaf_rn(xa.y, wa.y, acc);
      acc = __fmaf_rn(xa.z, wa.z, acc); acc = __fmaf_rn(xa.w, wa.w, acc);
      acc = __fmaf_rn(xb.x, wb.x, acc); acc = __fmaf_rn(xb.y, wb.y, acc);
      acc = __fmaf_rn(xb.z, wb.z, acc); acc = __fmaf_rn(xb.w, wb.w, acc);
      acc = __fmaf_rn(xc.x, wc.x, acc); acc = __fmaf_rn(xc.y, wc.y, acc);
      acc = __fmaf_rn(xc.z, wc.z, acc); acc = __fmaf_rn(xc.w, wc.w, acc);
      acc = __fmaf_rn(xd.x, wd.x, acc); acc = __fmaf_rn(xd.y, wd.y, acc);
      acc = __fmaf_rn(xd.z, wd.z, acc); acc = __fmaf_rn(xd.w, wd.w, acc);
    }
    {
#pragma clang fp contract(off)
      const float sq = acc * acc;
      float rr[8];
#pragma unroll
      for (int j = 0; j < 8; ++j) rr[j] = __shfl(sq, j);
      for (int i = 8; i < 64; i += 8) {
#pragma unroll
        for (int j = 0; j < 8; ++j) rr[j] += __shfl(sq, i + j);
      }
      const float ss = ((rr[0] + rr[1]) + (rr[2] + rr[3])) +
                       ((rr[4] + rr[5]) + (rr[6] + rr[7]));
      const float nrm = __fsqrt_rn(ss);
      const float s = fminf(1.0f, 0.99999f / fmaxf(nrm, 1e-12f));
      const float c0 = __shfl(acc, 0) * s;
      const float c1 = __shfl(acc, 1) * s;
      const float cr = (float)atan2((double)c1, (double)c0);
      const float fd = fdlibm_atan2f(c1, c0);
      const float tol = fmaxf(fabsf(cr) * 6e-7f, 1e-30f);
      const float ang = (fabsf(fd - cr) <= tol) ? fd : cr;
      const float t = ((ang / 6.2831854820251465f) + 0.5f) * 512.0f;
      int b = (int)floorf(t);
      b = b < 0 ? 0 : (b > 511 ? 511 : b);
      if (d == 0) (isk ? kb : qb)[(h << 12) + n] = b;
    }
  }
}

// ---------------------------------------------------------------------------
// Candidate selection, inverted (R6 post-mortem: the 64-chunk full scan per
// query never early-exits since ~24 matches < CAND; 112 µs latency-bound).
// (1) per-head histogram + unordered append of key indices to per-bin lists;
// (2) insertion-sort each bin list ascending (restores key-index order);
// (3) per (h,q): 3-way merge of bins {b-1,b,b+1}, first CANDN by index.
// ---------------------------------------------------------------------------
__global__ __launch_bounds__(256) void bin_hist_kernel(
    const int* __restrict__ kb, int* __restrict__ ghist, u16* __restrict__ blist)
{
  const int h = blockIdx.x;
  __shared__ int lhist[NBINS];
  for (int i = threadIdx.x; i < NBINS; i += 256) lhist[i] = 0;
  __syncthreads();
  for (int i = threadIdx.x; i < N_TOK; i += 256) {
    const int b = kb[(h << 12) + i];
    const int pos = atomicAdd(&lhist[b], 1);
    if (pos < BINCAP) blist[(((h << 9) + b) << 6) + pos] = (u16)i;
  }
  __syncthreads();
  for (int i = threadIdx.x; i < NBINS; i += 256)
    ghist[(h << 9) + i] = lhist[i] < BINCAP ? lhist[i] : BINCAP;
}

__global__ __launch_bounds__(256) void bin_sort_kernel(
    const int* __restrict__ ghist, u16* __restrict__ blist)
{
  __shared__ u16 buf[256][66];  // row stride 66 u16 = 33 words: conflict-free
  const int idx = blockIdx.x * 256 + threadIdx.x;  // 0..4095 = (h<<9)|b
  const int c = ghist[idx];
  u16* list = blist + (idx << 6);
  u16 (&a)[66] = buf[threadIdx.x];
  for (int i = 0; i < c; ++i) a[i] = list[i];
  for (int i = 1; i < c; ++i) {
    const u16 key = a[i];
    int j = i - 1;
    while (j >= 0 && a[j] > key) { a[j + 1] = a[j]; --j; }
    a[j + 1] = key;
  }
  for (int i = 0; i < c; ++i) list[i] = a[i];
}

__global__ __launch_bounds__(256) void cand_merge_kernel(
    const int* __restrict__ qb, const int* __restrict__ ghist,
    const u16* __restrict__ blist, int* __restrict__ cnt, u16* __restrict__ cand)
{
  const int hq = blockIdx.x * 256 + threadIdx.x;  // 0..32767
  const int h = hq >> 12;
  const int b = qb[hq];

  const u16* L[3]; int C[3]; int nl = 0;
#pragma unroll
  for (int db = -1; db <= 1; ++db) {
    const int bb = b + db;
    if (bb >= 0 && bb < NBINS) {
      const int c = ghist[(h << 9) + bb];
      if (c > 0) { L[nl] = blist + (((h << 9) + bb) << 6); C[nl] = c; ++nl; }
    }
  }
  int p[3] = {0, 0, 0};
  int v[3];
#pragma unroll
  for (int l = 0; l < 3; ++l) v[l] = (l < nl) ? (int)L[l][0] : 0x10000;

  int r = 0;
  while (r < CANDN) {
    int best = 0;
    if (v[1] < v[best]) best = 1;
    if (v[2] < v[best]) best = 2;
    const int mv = v[best];
    if (mv == 0x10000) break;
    cand[(hq << 6) + r] = (u16)mv;
    ++r;
    const int np = ++p[best];
    v[best] = (np < C[best]) ? (int)L[best][np] : 0x10000;
  }
  cnt[hq] = r;
}

// ---------------------------------------------------------------------------
// Attention: phase 1 lane=candidate (LDS-broadcast Q, float4 K rows, no
// shuffles in loop), wave softmax, LDS transpose, phase 2 lane=dim.
// ---------------------------------------------------------------------------
__global__ __launch_bounds__(256) void attn_kernel(
    const float* __restrict__ Qp, const float* __restrict__ Kp,
    const u16* __restrict__ Vb, const int* __restrict__ cnt,
    const u16* __restrict__ cand, u16* __restrict__ aout)
{
  __shared__ float s_q[4][64];
  __shared__ float s_attn[4][64];
  __shared__ int   s_ci[4][64];

  const int w    = threadIdx.x >> 6;
  const int lane = threadIdx.x & 63;
  const int wid  = blockIdx.x * 4 + w;
  const int h = wid >> 12;
  const int q = wid & 4095;
  const int hq = (h << 12) + q;

  int c = cnt[hq];
  int myc;
  if (c == 0) { myc = lane; c = 64; }
  else myc = (lane < c) ? (int)cand[(hq << 6) + lane] : 0;

  s_q[w][lane] = Qp[(hq << 6) + lane];
  s_ci[w][lane] = myc;
  __syncthreads();

  const float* krow = Kp + (((h << 12) + myc) << 6);
  float sc = 0.0f;
#pragma unroll
  for (int d = 0; d < HDIM; d += 4) {
    const float4 kv = *(const float4*)(krow + d);
    sc = fmaf(s_q[w][d + 0], kv.x, sc);
    sc = fmaf(s_q[w][d + 1], kv.y, sc);
    sc = fmaf(s_q[w][d + 2], kv.z, sc);
    sc = fmaf(s_q[w][d + 3], kv.w, sc);
  }
  sc = (lane < c) ? sc * ATT_SCALE : -INFINITY;

  float m = sc;
#pragma unroll
  for (int o = 32; o; o >>= 1) m = fmaxf(m, __shfl_xor(m, o));
  float p = (lane < c) ? expf(sc - m) : 0.0f;
  float sum = p;
#pragma unroll
  for (int o = 32; o; o >>= 1) sum += __shfl_xor(sum, o);
  s_attn[w][lane] = p / sum;
  __syncthreads();

  const u16* vbase = Vb + (h << 18);
  float out = 0.0f;
  for (int i = 0; i < c; ++i) {
    const float ai = s_attn[w][i];
    const int ci = s_ci[w][i];
    out = fmaf(ai, bf2f(vbase[(ci << 6) + lane]), out);
  }
  aout[q * DMODEL + (h << 6) + lane] = f2bf(out);
}

extern "C" void kernel_launch(void* const* d_in, const int* in_sizes, int n_in,
                              void* d_out, int out_size, void* d_ws, size_t ws_size,
                              hipStream_t stream) {
  const float* query = (const float*)d_in[0];
  const float* key_  = (const float*)d_in[1];
  const float* value = (const float*)d_in[2];
  const float* Wq = (const float*)d_in[3];
  const float* bq = (const float*)d_in[4];
  const float* Wk = (const float*)d_in[5];
  const float* bk = (const float*)d_in[6];
  const float* Wv = (const float*)d_in[7];
  const float* bv = (const float*)d_in[8];
  const float* Wo = (const float*)d_in[9];
  const float* bo = (const float*)d_in[10];

  char* ws = (char*)d_ws;
  float* Qp   = (float*)(ws);                // 8 MB: [h][n][64] f32 (projected)
  float* Kp   = (float*)(ws + 8388608);      // 8 MB (projected)
  u16*   Vb   = (u16*)(ws + 16777216);       // 4 MB: [h][n][64] bf16
  int*   qb   = (int*)(ws + 20971520);       // 128 KB
  int*   kb   = (int*)(ws + 21102592);       // 128 KB
  int*   cnt  = (int*)(ws + 21233664);       // 128 KB
  u16*   cand = (u16*)(ws + 21364736);       // 4 MB
  u16*   aout = (u16*)(ws + 25559040);       // 4 MB
  int*   wl_count = (int*)(ws + 29753344);   // 4 B
  int*   wl   = (int*)(ws + 29753348);       // 32 KB
  int*   ghist = (int*)(ws + 29786120);      // 16 KB: [h][512] int
  u16*   blist = (u16*)(ws + 29802504);      // 512 KB: [h][512][64] u16
  // total ~30.33 MB

  wl_init_kernel<<<1, 1, 0, stream>>>(wl_count);
  gemm_qkv_kernel<<<dim3(32, 4, 3), 256, 0, stream>>>(
      query, key_, value, Wq, bq, Wk, bk, Wv, bv, Qp, Kp, Vb);
  bins_pass1_kernel<<<256, 256, 0, stream>>>(query, key_, Wq, Wk, qb, kb, wl_count, wl);
  bins_pass2_kernel<<<64, 256, 0, stream>>>(query, key_, Wq, Wk, qb, kb, wl_count, wl);
  bin_hist_kernel<<<8, 256, 0, stream>>>(kb, ghist, blist);
  bin_sort_kernel<<<16, 256, 0, stream>>>(ghist, blist);
  cand_merge_kernel<<<128, 256, 0, stream>>>(qb, ghist, blist, cnt, cand);
  attn_kernel<<<8192, 256, 0, stream>>>(Qp, Kp, Vb, cnt, cand, aout);
  gemm_out_kernel<<<dim3(32, 4), 256, 0, stream>>>(aout, Wo, bo, (float*)d_out);
}

// Round 8
// 239.833 us; speedup vs baseline: 1.7253x; 1.1396x over previous
//
#include <hip/hip_runtime.h>
#include <math.h>

typedef unsigned short u16;
typedef __attribute__((ext_vector_type(8))) short v8bf;
typedef __attribute__((ext_vector_type(4))) float f32x4;

#define N_TOK 4096
#define DMODEL 512
#define NHEAD 8
#define HDIM 64
#define CANDN 64
#define NBINS 512
#define BINCAP 64
#define QCAP 128
#define ATT_SCALE 0.125f
#define MAX_NORM_F 0.99999f
#define WL_CAP 8192

__device__ __forceinline__ float bf2f(u16 u) {
  union { unsigned int i; float f; } v; v.i = ((unsigned int)u) << 16; return v.f;
}
__device__ __forceinline__ u16 f2bf(float f) {
  union { float f; unsigned int i; } v; v.f = f;
  unsigned int x = v.i;
  return (u16)((x + 0x7fffu + ((x >> 16) & 1u)) >> 16);
}
__device__ __forceinline__ uint4 load_pack8(const float* __restrict__ p) {
  const float4 x0 = *(const float4*)p;
  const float4 x1 = *(const float4*)(p + 4);
  union { u16 h[8]; uint4 u; } r;
  r.h[0] = f2bf(x0.x); r.h[1] = f2bf(x0.y); r.h[2] = f2bf(x0.z); r.h[3] = f2bf(x0.w);
  r.h[4] = f2bf(x1.x); r.h[5] = f2bf(x1.y); r.h[6] = f2bf(x1.z); r.h[7] = f2bf(x1.w);
  return r.u;
}

// ---------------------------------------------------------------------------
// GEMM 128x128 tile, BK=32, 4 waves x (4x4) 16x16x32 bf16 MFMAs.
// Poincare projection fused into Q/K epilogue (quad-group shfl_xor norm).
// ---------------------------------------------------------------------------
__global__ __launch_bounds__(256) void gemm_qkv_kernel(
    const float* __restrict__ query, const float* __restrict__ key_, const float* __restrict__ value,
    const float* __restrict__ Wq, const float* __restrict__ bq,
    const float* __restrict__ Wk, const float* __restrict__ bk,
    const float* __restrict__ Wv, const float* __restrict__ bv,
    float* __restrict__ Qp, float* __restrict__ Kp, u16* __restrict__ Vb)
{
  const int z = blockIdx.z;
  const float* A    = (z == 0) ? query : (z == 1) ? key_ : value;
  const float* W    = (z == 0) ? Wq    : (z == 1) ? Wk   : Wv;
  const float* bias = (z == 0) ? bq    : (z == 1) ? bk   : bv;

  __shared__ u16 As[128 * 40];
  __shared__ u16 Ws[128 * 40];

  const int tid  = threadIdx.x;
  const int lane = tid & 63;
  const int wave = tid >> 6;
  const int row4 = tid >> 2;
  const int seg  = tid & 3;

  const int bm = blockIdx.x * 128;
  const int bn = blockIdx.y * 128;
  const int wm = (wave & 1) * 64;
  const int wn = (wave >> 1) * 64;
  const int l15 = lane & 15;
  const int quad = lane >> 4;

  f32x4 acc[4][4] = {};

  for (int kt = 0; kt < DMODEL; kt += 32) {
    uint4 a0 = load_pack8(A + (bm + row4) * DMODEL + kt + seg * 8);
    uint4 a1 = load_pack8(A + (bm + row4 + 64) * DMODEL + kt + seg * 8);
    uint4 w0 = load_pack8(W + (bn + row4) * DMODEL + kt + seg * 8);
    uint4 w1 = load_pack8(W + (bn + row4 + 64) * DMODEL + kt + seg * 8);
    __syncthreads();
    *(uint4*)&As[row4 * 40 + seg * 8] = a0;
    *(uint4*)&As[(row4 + 64) * 40 + seg * 8] = a1;
    *(uint4*)&Ws[row4 * 40 + seg * 8] = w0;
    *(uint4*)&Ws[(row4 + 64) * 40 + seg * 8] = w1;
    __syncthreads();
    v8bf af[4], bfr[4];
#pragma unroll
    for (int i = 0; i < 4; ++i)
      af[i] = *(const v8bf*)&As[(wm + i * 16 + l15) * 40 + quad * 8];
#pragma unroll
    for (int j = 0; j < 4; ++j)
      bfr[j] = *(const v8bf*)&Ws[(wn + j * 16 + l15) * 40 + quad * 8];
#pragma unroll
    for (int i = 0; i < 4; ++i)
#pragma unroll
      for (int j = 0; j < 4; ++j)
        acc[i][j] = __builtin_amdgcn_mfma_f32_16x16x32_bf16(af[i], bfr[j], acc[i][j], 0, 0, 0);
  }

  float bval[4];
#pragma unroll
  for (int j = 0; j < 4; ++j) bval[j] = bias[bn + wn + j * 16 + l15];
  const int h = (bn + wn) >> 6;

#pragma unroll
  for (int i = 0; i < 4; ++i) {
#pragma unroll
    for (int r = 0; r < 4; ++r) {
      const int row = bm + wm + i * 16 + quad * 4 + r;
      float v0 = acc[i][0][r] + bval[0];
      float v1 = acc[i][1][r] + bval[1];
      float v2 = acc[i][2][r] + bval[2];
      float v3 = acc[i][3][r] + bval[3];
      if (z != 2) {
        float ss = v0 * v0 + v1 * v1 + v2 * v2 + v3 * v3;
#pragma unroll
        for (int o = 1; o < 16; o <<= 1) ss += __shfl_xor(ss, o);
        const float s = fminf(1.0f, MAX_NORM_F / fmaxf(sqrtf(ss), 1e-12f));
        v0 *= s; v1 *= s; v2 *= s; v3 *= s;
      }
      const int base = (((h << 12) + row) << 6) + l15;
      if (z == 2) {
        Vb[base +  0] = f2bf(v0); Vb[base + 16] = f2bf(v1);
        Vb[base + 32] = f2bf(v2); Vb[base + 48] = f2bf(v3);
      } else {
        float* P = z ? Kp : Qp;
        P[base +  0] = v0; P[base + 16] = v1;
        P[base + 32] = v2; P[base + 48] = v3;
      }
    }
  }
}

__global__ __launch_bounds__(256) void gemm_out_kernel(
    const u16* __restrict__ A, const float* __restrict__ W,
    const float* __restrict__ bias, float* __restrict__ O)
{
  __shared__ u16 As[128 * 40];
  __shared__ u16 Ws[128 * 40];

  const int tid  = threadIdx.x;
  const int lane = tid & 63;
  const int wave = tid >> 6;
  const int row4 = tid >> 2;
  const int seg  = tid & 3;

  const int bm = blockIdx.x * 128;
  const int bn = blockIdx.y * 128;
  const int wm = (wave & 1) * 64;
  const int wn = (wave >> 1) * 64;
  const int l15 = lane & 15;
  const int quad = lane >> 4;

  f32x4 acc[4][4] = {};

  for (int kt = 0; kt < DMODEL; kt += 32) {
    uint4 a0 = *(const uint4*)(A + (bm + row4) * DMODEL + kt + seg * 8);
    uint4 a1 = *(const uint4*)(A + (bm + row4 + 64) * DMODEL + kt + seg * 8);
    uint4 w0 = load_pack8(W + (bn + row4) * DMODEL + kt + seg * 8);
    uint4 w1 = load_pack8(W + (bn + row4 + 64) * DMODEL + kt + seg * 8);
    __syncthreads();
    *(uint4*)&As[row4 * 40 + seg * 8] = a0;
    *(uint4*)&As[(row4 + 64) * 40 + seg * 8] = a1;
    *(uint4*)&Ws[row4 * 40 + seg * 8] = w0;
    *(uint4*)&Ws[(row4 + 64) * 40 + seg * 8] = w1;
    __syncthreads();
    v8bf af[4], bfr[4];
#pragma unroll
    for (int i = 0; i < 4; ++i)
      af[i] = *(const v8bf*)&As[(wm + i * 16 + l15) * 40 + quad * 8];
#pragma unroll
    for (int j = 0; j < 4; ++j)
      bfr[j] = *(const v8bf*)&Ws[(wn + j * 16 + l15) * 40 + quad * 8];
#pragma unroll
    for (int i = 0; i < 4; ++i)
#pragma unroll
      for (int j = 0; j < 4; ++j)
        acc[i][j] = __builtin_amdgcn_mfma_f32_16x16x32_bf16(af[i], bfr[j], acc[i][j], 0, 0, 0);
  }

#pragma unroll
  for (int j = 0; j < 4; ++j) {
    const int cg = bn + wn + j * 16 + l15;
    const float bval = bias[cg];
#pragma unroll
    for (int i = 0; i < 4; ++i) {
      const int rbase = bm + wm + i * 16 + quad * 4;
#pragma unroll
      for (int r = 0; r < 4; ++r)
        O[(rbase + r) * DMODEL + cg] = acc[i][j][r] + bval;
    }
  }
}

// ---------------------------------------------------------------------------
// Bins pass 1 (restructured for coalescing — R7 post-mortem: row-per-thread
// gave 64 distinct cache lines per float4 instr, ~40 µs TA-bound). Block
// stages a 16-row X tile in LDS (coalesced float4 loads); threads t: 16
// consecutive t share one X row (LDS broadcast) and cover 8 heads x 2 coords.
// f64 accumulate in 4 ILP chains; partner lanes exchange a0/a1 via shfl_xor.
// Detector margin unchanged (covers f64 ordering slop trivially).
// ---------------------------------------------------------------------------
__global__ void wl_init_kernel(int* __restrict__ wl_count) { *wl_count = 0; }

__global__ __launch_bounds__(256) void bins_pass1_kernel(
    const float* __restrict__ query, const float* __restrict__ key_,
    const float* __restrict__ Wq, const float* __restrict__ Wk,
    int* __restrict__ qb, int* __restrict__ kb,
    int* __restrict__ wl_count, int* __restrict__ wl)
{
  __shared__ float xs[16 * 516];
  const int isk  = blockIdx.y;
  const int tile = blockIdx.x;
  const float* X = isk ? key_ : query;
  const float* W = isk ? Wk : Wq;
  const int tid = threadIdx.x;

#pragma unroll
  for (int i = 0; i < 8; ++i) {
    const int flat = i * 1024 + tid * 4;
    const int row = flat >> 9, col = flat & 511;
    *(float4*)&xs[row * 516 + col] = *(const float4*)(X + (tile * 16 + row) * DMODEL + col);
  }
  __syncthreads();

  const int n_local = tid >> 4;
  const int pair = tid & 15;
  const int h = pair >> 1, coord = pair & 1;
  const float* wrow = W + ((h << 6) + coord) * DMODEL;
  const float* xrow = &xs[n_local * 516];

  double c0 = 0.0, c1 = 0.0, c2 = 0.0, c3 = 0.0;
  for (int k = 0; k < DMODEL; k += 4) {
    const float4 xv = *(const float4*)(xrow + k);
    const float4 wv = *(const float4*)(wrow + k);
    c0 = fma((double)xv.x, (double)wv.x, c0);
    c1 = fma((double)xv.y, (double)wv.y, c1);
    c2 = fma((double)xv.z, (double)wv.z, c2);
    c3 = fma((double)xv.w, (double)wv.w, c3);
  }
  const double a = (c0 + c1) + (c2 + c3);
  const double other = __shfl_xor(a, 1);
  if (coord == 0) {
    const double a0 = a, a1 = other;
    const int n = tile * 16 + n_local;
    double ang = atan2(a1, a0);
    double t = (ang / 6.283185307179586 + 0.5) * 512.0;
    int b = (int)floor(t);
    b = b < 0 ? 0 : (b > 511 ? 511 : b);
    (isk ? kb : qb)[(h << 12) + n] = b;

    const double r = sqrt(a0 * a0 + a1 * a1);
    const double dist = fabs(t - nearbyint(t));
    const double margin = fmin(0.45, 3.3e-4 / fmax(r, 1e-30) + 5e-5);
    if (dist < margin) {
      int idx = atomicAdd(wl_count, 1);
      if (idx < WL_CAP) wl[idx] = (isk << 15) | (h << 12) | n;
    }
  }
}

__device__ float fdlibm_atanf(float x) {
#pragma clang fp contract(off)
  const float atanhi[4] = {4.6364760399e-01f, 7.8539812565e-01f,
                           9.8279368877e-01f, 1.5707962513e+00f};
  const float atanlo[4] = {5.0121582440e-09f, 3.7748947079e-08f,
                           3.4473217170e-08f, 7.5497894159e-08f};
  const float aT[5] = {3.3333328366e-01f, -1.9999158382e-01f, 1.4253635705e-01f,
                       -1.0648017377e-01f, 6.1687607318e-02f};
  unsigned ix = __float_as_uint(x);
  const unsigned sign = ix >> 31;
  ix &= 0x7fffffffu;
  int id;
  float z, w, s1, s2;
  if (ix >= 0x4c800000u) {
    z = atanhi[3] + 0x1p-120f;
    return sign ? -z : z;
  }
  if (ix < 0x3ee00000u) {
    if (ix < 0x39800000u) return x;
    id = -1;
  } else {
    x = fabsf(x);
    if (ix < 0x3f980000u) {
      if (ix < 0x3f300000u) { id = 0; x = (2.0f * x - 1.0f) / (2.0f + x); }
      else                  { id = 1; x = (x - 1.0f) / (x + 1.0f); }
    } else {
      if (ix < 0x401c0000u) { id = 2; x = (x - 1.5f) / (1.0f + 1.5f * x); }
      else                  { id = 3; x = -1.0f / x; }
    }
  }
  z = x * x;
  w = z * z;
  s1 = z * (aT[0] + w * (aT[2] + w * aT[4]));
  s2 = w * (aT[1] + w * aT[3]);
  if (id < 0) return x - x * (s1 + s2);
  z = atanhi[id] - ((x * (s1 + s2) - atanlo[id]) - x);
  return sign ? -z : z;
}

__device__ float fdlibm_atan2f(float y, float x) {
#pragma clang fp contract(off)
  const float pi = 3.1415927410e+00f, pi_lo = -8.7422776573e-08f;
  const unsigned hx = __float_as_uint(x), hy = __float_as_uint(y);
  if (hx == 0x3f800000u) return fdlibm_atanf(y);
  const unsigned m = ((hy >> 31) & 1u) | ((hx >> 30) & 2u);
  const unsigned ix = hx & 0x7fffffffu, iy = hy & 0x7fffffffu;
  if (iy == 0u) {
    switch (m) { case 0: case 1: return y; case 2: return pi; default: return -pi; }
  }
  if (ix == 0u) return (m & 1u) ? -1.57079637050628662f : 1.57079637050628662f;
  float z;
  if (ix + (26u << 23) < iy) {
    z = 1.57079637050628662f;
    return (m & 1u) ? -z : z;
  }
  if ((m & 2u) && iy + (26u << 23) < ix) z = 0.0f;
  else z = fdlibm_atanf(fabsf(y / x));
  switch (m) {
    case 0: return z;
    case 1: return -z;
    case 2: return pi - (z - pi_lo);
    default: return (z - pi_lo) - pi;
  }
}

__global__ __launch_bounds__(256) void bins_pass2_kernel(
    const float* __restrict__ query, const float* __restrict__ key_,
    const float* __restrict__ Wq, const float* __restrict__ Wk,
    int* __restrict__ qb, int* __restrict__ kb,
    const int* __restrict__ wl_count, const int* __restrict__ wl)
{
  int cnt_ = *wl_count;
  if (cnt_ > WL_CAP) cnt_ = WL_CAP;
  const int w = threadIdx.x >> 6;
  const int d = threadIdx.x & 63;
  for (int e = blockIdx.x * 4 + w; e < cnt_; e += gridDim.x * 4) {
    const int code = wl[e];
    const int n = code & 4095;
    const int h = (code >> 12) & 7;
    const int isk = (code >> 15) & 1;
    const float* xr = (isk ? key_ : query) + n * DMODEL;
    const float* wr = (isk ? Wk : Wq) + (h * 64 + d) * DMODEL;
    float acc = 0.0f;
    for (int k = 0; k < DMODEL; k += 16) {
      const float4 xa = *(const float4*)(xr + k);
      const float4 xb = *(const float4*)(xr + k + 4);
      const float4 xc = *(const float4*)(xr + k + 8);
      const float4 xd = *(const float4*)(xr + k + 12);
      const float4 wa = *(const float4*)(wr + k);
      const float4 wb = *(const float4*)(wr + k + 4);
      const float4 wc = *(const float4*)(wr + k + 8);
      const float4 wd = *(const float4*)(wr + k + 12);
      acc = __fmaf_rn(xa.x, wa.x, acc); acc = __fmaf_rn(xa.y, wa.y, acc);
      acc = __fmaf_rn(xa.z, wa.z, acc); acc = __fmaf_rn(xa.w, wa.w, acc);
      acc = __fmaf_rn(xb.x, wb.x, acc); acc = __fmaf_rn(xb.y, wb.y, acc);
      acc = __fmaf_rn(xb.z, wb.z, acc); acc = __fmaf_rn(xb.w, wb.w, acc);
      acc = __fmaf_rn(xc.x, wc.x, acc); acc = __fmaf_rn(xc.y, wc.y, acc);
      acc = __fmaf_rn(xc.z, wc.z, acc); acc = __fmaf_rn(xc.w, wc.w, acc);
      acc = __fmaf_rn(xd.x, wd.x, acc); acc = __fmaf_rn(xd.y, wd.y, acc);
      acc = __fmaf_rn(xd.z, wd.z, acc); acc = __fmaf_rn(xd.w, wd.w, acc);
    }
    {
#pragma clang fp contract(off)
      const float sq = acc * acc;
      float rr[8];
#pragma unroll
      for (int j = 0; j < 8; ++j) rr[j] = __shfl(sq, j);
      for (int i = 8; i < 64; i += 8) {
#pragma unroll
        for (int j = 0; j < 8; ++j) rr[j] += __shfl(sq, i + j);
      }
      const float ss = ((rr[0] + rr[1]) + (rr[2] + rr[3])) +
                       ((rr[4] + rr[5]) + (rr[6] + rr[7]));
      const float nrm = __fsqrt_rn(ss);
      const float s = fminf(1.0f, 0.99999f / fmaxf(nrm, 1e-12f));
      const float c0 = __shfl(acc, 0) * s;
      const float c1 = __shfl(acc, 1) * s;
      const float cr = (float)atan2((double)c1, (double)c0);
      const float fd = fdlibm_atan2f(c1, c0);
      const float tol = fmaxf(fabsf(cr) * 6e-7f, 1e-30f);
      const float ang = (fabsf(fd - cr) <= tol) ? fd : cr;
      const float t = ((ang / 6.2831854820251465f) + 0.5f) * 512.0f;
      int b = (int)floorf(t);
      b = b < 0 ? 0 : (b > 511 ? 511 : b);
      if (d == 0) (isk ? kb : qb)[(h << 12) + n] = b;
    }
  }
}

// ---------------------------------------------------------------------------
// Histogram keys AND queries into per-(h,bin) lists. Keys (cap 64) get
// sorted (order defines candidate truncation); query lists (cap 128) need
// no order (each query independent).
// ---------------------------------------------------------------------------
__global__ __launch_bounds__(256) void bin_hist_kernel(
    const int* __restrict__ kb, const int* __restrict__ qb,
    int* __restrict__ ghist, u16* __restrict__ blist,
    int* __restrict__ qhist, u16* __restrict__ qlist)
{
  const int h = blockIdx.x;
  const int type = blockIdx.y;  // 0 = keys, 1 = queries
  const int* src = type ? qb : kb;
  int* hist = type ? qhist : ghist;
  u16* list = type ? qlist : blist;
  const int cap = type ? QCAP : BINCAP;
  const int stride = type ? QCAP : BINCAP;

  __shared__ int lhist[NBINS];
  for (int i = threadIdx.x; i < NBINS; i += 256) lhist[i] = 0;
  __syncthreads();
  for (int i = threadIdx.x; i < N_TOK; i += 256) {
    const int b = src[(h << 12) + i];
    const int pos = atomicAdd(&lhist[b], 1);
    if (pos < cap) list[((h << 9) + b) * stride + pos] = (u16)i;
  }
  __syncthreads();
  for (int i = threadIdx.x; i < NBINS; i += 256)
    hist[(h << 9) + i] = lhist[i] < cap ? lhist[i] : cap;
}

__global__ __launch_bounds__(256) void bin_sort_kernel(
    const int* __restrict__ ghist, u16* __restrict__ blist)
{
  __shared__ u16 buf[256][66];
  const int idx = blockIdx.x * 256 + threadIdx.x;  // (h<<9)|b
  const int c = ghist[idx];
  u16* list = blist + (idx << 6);
  u16 (&a)[66] = buf[threadIdx.x];
  for (int i = 0; i < c; ++i) a[i] = list[i];
  for (int i = 1; i < c; ++i) {
    const u16 key = a[i];
    int j = i - 1;
    while (j >= 0 && a[j] > key) { a[j + 1] = a[j]; --j; }
    a[j + 1] = key;
  }
  for (int i = 0; i < c; ++i) list[i] = a[i];
}

// Candidate list per (h,bin) only — identical for every query in the bin
// (first CANDN by key index of the 3-bin union). 4096 merges vs 32768.
__global__ __launch_bounds__(256) void cand_merge_kernel(
    const int* __restrict__ ghist, const u16* __restrict__ blist,
    int* __restrict__ ccntb, u16* __restrict__ candb)
{
  const int hb = blockIdx.x * 256 + threadIdx.x;  // 0..4095
  const int h = hb >> 9;
  const int b = hb & 511;

  const u16* L[3]; int C[3]; int nl = 0;
#pragma unroll
  for (int db = -1; db <= 1; ++db) {
    const int bb = b + db;
    if (bb >= 0 && bb < NBINS) {
      const int c = ghist[(h << 9) + bb];
      if (c > 0) { L[nl] = blist + (((h << 9) + bb) << 6); C[nl] = c; ++nl; }
    }
  }
  int p[3] = {0, 0, 0};
  int v[3];
#pragma unroll
  for (int l = 0; l < 3; ++l) v[l] = (l < nl) ? (int)L[l][0] : 0x10000;

  int r = 0;
  while (r < CANDN) {
    int best = 0;
    if (v[1] < v[best]) best = 1;
    if (v[2] < v[best]) best = 2;
    const int mv = v[best];
    if (mv == 0x10000) break;
    candb[(hb << 6) + r] = (u16)mv;
    ++r;
    const int np = ++p[best];
    v[best] = (np < C[best]) ? (int)L[best][np] : 0x10000;
  }
  ccntb[hb] = r;
}

// ---------------------------------------------------------------------------
// Bin-batched MFMA attention (R7 post-mortem: per-query K gather was TA-
// bound, 64 lines/instr). One wave per (h,bin): gather candidate K (f32->
// bf16 A-frag order) and V (bf16 B-frag order) into LDS ONCE, then per
// 16-query chunk: S = K x Q^T (MFMA, D: row=key col=query), softmax across
// quads, P->LDS->A-frag, O = P x V (MFMA, D: row=query col=dim).
// ---------------------------------------------------------------------------
__global__ __launch_bounds__(64) void attn_bin_kernel(
    const float* __restrict__ Qp, const float* __restrict__ Kp,
    const u16* __restrict__ Vb, const int* __restrict__ qhist,
    const u16* __restrict__ qlist, const int* __restrict__ ccntb,
    const u16* __restrict__ candb, u16* __restrict__ aout)
{
  __shared__ u16 kf[4 * 2 * 4 * 16 * 8];   // A-frag order: [t][ks][quad][m][j]
  __shared__ u16 vf[4 * 2 * 4 * 16 * 8];   // B-frag order: [nt][ks][quad][d15][j]
  __shared__ u16 pf[16 * 72];              // P[q][key], row stride 72 u16
  __shared__ u16 s_cand[64];
  __shared__ int s_qg[16];

  const int hb = blockIdx.x;               // (h<<9)|b
  const int h = hb >> 9;
  const int qcnt = qhist[hb];
  if (qcnt == 0) return;

  const int lane = threadIdx.x;
  const int l15 = lane & 15;
  const int quad = lane >> 4;

  const int ccnt = ccntb[hb];
  const int ccnt_eff = (ccnt == 0) ? 64 : ccnt;
  s_cand[lane] = (ccnt == 0) ? (u16)lane
               : ((lane < ccnt) ? candb[(hb << 6) + lane] : candb[hb << 6]);
  __syncthreads();

  // Gather K rows -> bf16 A-frags (4 rows x 16 float4-segs per iteration)
  {
    const int r = lane >> 4, s = lane & 15;
    const int kstep = s >> 3, qd = (s >> 1) & 3, j0 = (s & 1) * 4;
#pragma unroll
    for (int it = 0; it < 16; ++it) {
      const int key = it * 4 + r;
      const int c = s_cand[key];
      const float4 kv = *(const float4*)(Kp + ((((h << 12) | c) << 6) + s * 4));
      union { u16 hh[4]; uint2 u; } pk;
      pk.hh[0] = f2bf(kv.x); pk.hh[1] = f2bf(kv.y);
      pk.hh[2] = f2bf(kv.z); pk.hh[3] = f2bf(kv.w);
      const int idx = ((((key >> 4) * 2 + kstep) * 4 + qd) * 16 + (key & 15)) * 8 + j0;
      *(uint2*)&kf[idx] = pk.u;
    }
  }
  // Gather V rows -> bf16 B-frags (8 rows x 8 16B-segs per iteration)
  {
    const int r = lane >> 3, s = lane & 7;
    const int nt = s >> 1, d0 = (s & 1) * 8;
#pragma unroll
    for (int it = 0; it < 8; ++it) {
      const int key = it * 8 + r;
      const int c = s_cand[key];
      union { u16 hh[8]; uint4 u; } vv;
      vv.u = *(const uint4*)(Vb + ((h << 18) | (c << 6)) + s * 8);
      const int kstep = key >> 5, qd = (key >> 3) & 3, j = key & 7;
#pragma unroll
      for (int m = 0; m < 8; ++m)
        vf[(((nt * 2 + kstep) * 4 + qd) * 16 + d0 + m) * 8 + j] = vv.hh[m];
    }
  }
  __syncthreads();

  v8bf akf[4][2], bvf[4][2];
#pragma unroll
  for (int t = 0; t < 4; ++t)
#pragma unroll
    for (int ks = 0; ks < 2; ++ks) {
      akf[t][ks] = *(const v8bf*)&kf[(((t * 2 + ks) * 4 + quad) * 16 + l15) * 8];
      bvf[t][ks] = *(const v8bf*)&vf[(((t * 2 + ks) * 4 + quad) * 16 + l15) * 8];
    }

  const int nchunk = (qcnt + 15) >> 4;
  for (int ci = 0; ci < nchunk; ++ci) {
    const int base = ci << 4;
    const int qcn = min(16, qcnt - base);
    __syncthreads();
    if (lane < 16) {
      int idx = base + lane;
      if (idx > qcnt - 1) idx = qcnt - 1;
      s_qg[lane] = (int)qlist[(hb << 7) + idx];
    }
    __syncthreads();

    // Q B-frags from global (lane&15 = query, 8 contiguous dims per frag)
    const float* qrow = Qp + (((h << 12) | s_qg[l15]) << 6);
    v8bf bq[2];
#pragma unroll
    for (int ks = 0; ks < 2; ++ks) {
      const float4 qa = *(const float4*)(qrow + ks * 32 + quad * 8);
      const float4 qb4 = *(const float4*)(qrow + ks * 32 + quad * 8 + 4);
      union { u16 hh[8]; v8bf v; } uq;
      uq.hh[0] = f2bf(qa.x); uq.hh[1] = f2bf(qa.y);
      uq.hh[2] = f2bf(qa.z); uq.hh[3] = f2bf(qa.w);
      uq.hh[4] = f2bf(qb4.x); uq.hh[5] = f2bf(qb4.y);
      uq.hh[6] = f2bf(qb4.z); uq.hh[7] = f2bf(qb4.w);
      bq[ks] = uq.v;
    }

    // S = K x Q^T : D row = key-in-tile, col = query
    float sc[16];
#pragma unroll
    for (int t = 0; t < 4; ++t) {
      f32x4 sa = {0.f, 0.f, 0.f, 0.f};
      sa = __builtin_amdgcn_mfma_f32_16x16x32_bf16(akf[t][0], bq[0], sa, 0, 0, 0);
      sa = __builtin_amdgcn_mfma_f32_16x16x32_bf16(akf[t][1], bq[1], sa, 0, 0, 0);
#pragma unroll
      for (int r = 0; r < 4; ++r) {
        const int key = t * 16 + quad * 4 + r;
        sc[t * 4 + r] = (key < ccnt_eff) ? sa[r] * ATT_SCALE : -INFINITY;
      }
    }
    // softmax per query column (16 regs + quad-combining shuffles)
    float mx = sc[0];
#pragma unroll
    for (int i = 1; i < 16; ++i) mx = fmaxf(mx, sc[i]);
    mx = fmaxf(mx, __shfl_xor(mx, 16));
    mx = fmaxf(mx, __shfl_xor(mx, 32));
    float sum = 0.0f;
    float pe[16];
#pragma unroll
    for (int i = 0; i < 16; ++i) { pe[i] = __expf(sc[i] - mx); sum += pe[i]; }
    sum += __shfl_xor(sum, 16);
    sum += __shfl_xor(sum, 32);
    const float inv = 1.0f / sum;

    __syncthreads();
#pragma unroll
    for (int t = 0; t < 4; ++t)
#pragma unroll
      for (int r = 0; r < 4; ++r)
        pf[l15 * 72 + t * 16 + quad * 4 + r] = f2bf(pe[t * 4 + r] * inv);
    __syncthreads();

    v8bf ap[2];
#pragma unroll
    for (int ks = 0; ks < 2; ++ks)
      ap[ks] = *(const v8bf*)&pf[l15 * 72 + ks * 32 + quad * 8];

    // O = P x V : D row = query, col = dim-in-tile
#pragma unroll
    for (int nt = 0; nt < 4; ++nt) {
      f32x4 o = {0.f, 0.f, 0.f, 0.f};
      o = __builtin_amdgcn_mfma_f32_16x16x32_bf16(ap[0], bvf[nt][0], o, 0, 0, 0);
      o = __builtin_amdgcn_mfma_f32_16x16x32_bf16(ap[1], bvf[nt][1], o, 0, 0, 0);
#pragma unroll
      for (int r = 0; r < 4; ++r) {
        const int row = quad * 4 + r;
        if (row < qcn)
          aout[s_qg[row] * DMODEL + (h << 6) + nt * 16 + l15] = f2bf(o[r]);
      }
    }
  }
}

extern "C" void kernel_launch(void* const* d_in, const int* in_sizes, int n_in,
                              void* d_out, int out_size, void* d_ws, size_t ws_size,
                              hipStream_t stream) {
  const float* query = (const float*)d_in[0];
  const float* key_  = (const float*)d_in[1];
  const float* value = (const float*)d_in[2];
  const float* Wq = (const float*)d_in[3];
  const float* bq = (const float*)d_in[4];
  const float* Wk = (const float*)d_in[5];
  const float* bk = (const float*)d_in[6];
  const float* Wv = (const float*)d_in[7];
  const float* bv = (const float*)d_in[8];
  const float* Wo = (const float*)d_in[9];
  const float* bo = (const float*)d_in[10];

  char* ws = (char*)d_ws;
  float* Qp    = (float*)(ws);               // 8 MB [h][n][64] f32 projected
  float* Kp    = (float*)(ws + 8388608);     // 8 MB
  u16*   Vb    = (u16*)(ws + 16777216);      // 4 MB [h][n][64] bf16
  int*   qb    = (int*)(ws + 20971520);      // 128 KB
  int*   kb    = (int*)(ws + 21102592);      // 128 KB
  int*   wl_count = (int*)(ws + 21233664);   // 64 B
  int*   wl    = (int*)(ws + 21233728);      // 32 KB
  int*   ghist = (int*)(ws + 21266496);      // 16 KB
  int*   qhist = (int*)(ws + 21282880);      // 16 KB
  u16*   blist = (u16*)(ws + 21299264);      // 512 KB [4096][64]
  u16*   qlist = (u16*)(ws + 21823552);      // 1 MB [4096][128]
  u16*   candb = (u16*)(ws + 22872128);      // 512 KB [4096][64]
  int*   ccntb = (int*)(ws + 23396416);      // 16 KB
  u16*   aout  = (u16*)(ws + 23412800);      // 4 MB [n][512] bf16
  // total ~26.3 MB

  wl_init_kernel<<<1, 1, 0, stream>>>(wl_count);
  gemm_qkv_kernel<<<dim3(32, 4, 3), 256, 0, stream>>>(
      query, key_, value, Wq, bq, Wk, bk, Wv, bv, Qp, Kp, Vb);
  bins_pass1_kernel<<<dim3(256, 2), 256, 0, stream>>>(query, key_, Wq, Wk, qb, kb, wl_count, wl);
  bins_pass2_kernel<<<64, 256, 0, stream>>>(query, key_, Wq, Wk, qb, kb, wl_count, wl);
  bin_hist_kernel<<<dim3(8, 2), 256, 0, stream>>>(kb, qb, ghist, blist, qhist, qlist);
  bin_sort_kernel<<<16, 256, 0, stream>>>(ghist, blist);
  cand_merge_kernel<<<16, 256, 0, stream>>>(ghist, blist, ccntb, candb);
  attn_bin_kernel<<<4096, 64, 0, stream>>>(Qp, Kp, Vb, qhist, qlist, ccntb, candb, aout);
  gemm_out_kernel<<<dim3(32, 4), 256, 0, stream>>>(aout, Wo, bo, (float*)d_out);
}